// Round 11
// baseline (260.948 us; speedup 1.0000x reference)
//
#include <hip/hip_runtime.h>
#include <hip/hip_bf16.h>

typedef __bf16 bf16x8 __attribute__((ext_vector_type(8)));
typedef float f32x4 __attribute__((ext_vector_type(4)));

__device__ __forceinline__ unsigned short f2b(float f) {
    union { float f; unsigned int u; } v; v.f = f;
    unsigned int r = (v.u + 0x7FFFu + ((v.u >> 16) & 1u)) >> 16;
    return (unsigned short)r;
}

__device__ __forceinline__ unsigned int cvtpk(float lo, float hi) {
    unsigned int r;
    asm("v_cvt_pk_bf16_f32 %0, %1, %2" : "=v"(r) : "v"(lo), "v"(hi));
    return r;
}

__device__ __forceinline__ void gload_lds16(const void* g, void* l) {
    __builtin_amdgcn_global_load_lds((__attribute__((address_space(1))) void*)g,
                                     (__attribute__((address_space(3))) void*)l,
                                     16, 0, 0);
}

// ---------------- converts ----------------

__global__ __launch_bounds__(256) void cvt_x_kernel(const float* __restrict__ in,
                                                    unsigned short* __restrict__ out) {
    int i = (blockIdx.x * 256 + threadIdx.x) * 4;
    float4 f = *(const float4*)(in + i);
    ushort4 u;
    u.x = f2b(f.x); u.y = f2b(f.y); u.z = f2b(f.z); u.w = f2b(f.w);
    *(ushort4*)(out + i) = u;
}

// in: R x C fp32, out: C x R bf16 (transposed)
__global__ __launch_bounds__(256) void transpose_cvt(const float* __restrict__ in,
                                                     unsigned short* __restrict__ out,
                                                     int R, int C) {
    __shared__ float t[32][33];
    int c0 = blockIdx.x * 32, r0 = blockIdx.y * 32;
    int tx = threadIdx.x, ty = threadIdx.y;
#pragma unroll
    for (int i = 0; i < 4; i++)
        t[ty + i * 8][tx] = in[(size_t)(r0 + ty + i * 8) * C + c0 + tx];
    __syncthreads();
#pragma unroll
    for (int i = 0; i < 4; i++)
        out[(size_t)(c0 + ty + i * 8) * R + r0 + tx] = f2b(t[tx][ty + i * 8]);
}

// V [bh][n][64] bf16 -> Vp [bh][64][n'] bf16, k columns permuted per 64-tile:
// src col c = 16n + 4g + r  ->  dst col g*16 + n*4 + r
__global__ __launch_bounds__(256) void vtrans_kernel(const unsigned short* __restrict__ V,
                                                     unsigned short* __restrict__ Vp) {
    __shared__ unsigned short t[64][72];
    int bh = blockIdx.y, n0 = blockIdx.x * 64;
    int r = threadIdx.x >> 2, gd = threadIdx.x & 3;
    const unsigned short* src = V + ((size_t)bh * 2048 + n0 + r) * 64 + gd * 16;
    *(bf16x8*)&t[r][gd * 16]     = *(const bf16x8*)src;
    *(bf16x8*)&t[r][gd * 16 + 8] = *(const bf16x8*)(src + 8);
    __syncthreads();
    unsigned short tmp[16];
#pragma unroll
    for (int m = 0; m < 16; m++)
        tmp[m] = t[16 * (m >> 2) + 4 * gd + (m & 3)][r];   // inv-perm gather
    unsigned short* dst = Vp + ((size_t)bh * 64 + r) * 2048 + n0 + gd * 16;
    *(bf16x8*)dst       = *(const bf16x8*)tmp;
    *(bf16x8*)(dst + 8) = *(const bf16x8*)(tmp + 8);
}

// ---------------- gates: sigmoid(x @ w_gates) -> [b*16+h][n]; also zeroes the
// work-stealing counter consumed by attn_kernel (runs earlier in the stream) --

__global__ __launch_bounds__(256) void gates_kernel(const float* __restrict__ x,
                                                    const float* __restrict__ wg,
                                                    float* __restrict__ gates,
                                                    unsigned int* __restrict__ ctr) {
    if (blockIdx.x == 0 && threadIdx.x == 0) *ctr = 0u;
    int row = blockIdx.x;            // 0..4095  (b*2048+n)
    int b = row >> 11, n = row & 2047;
    int t = threadIdx.x;
    int h = t & 15, fi = t >> 4;     // fi 0..15
    const float* xr = x + (size_t)row * 1024;
    float s = 0.f;
    for (int f = fi; f < 1024; f += 16)
        s += xr[f] * wg[f * 16 + h];
    __shared__ float red[16][17];
    red[fi][h] = s;
    __syncthreads();
    if (t < 16) {
        float tot = 0.f;
#pragma unroll
        for (int i = 0; i < 16; i++) tot += red[i][t];
        float g = 1.f / (1.f + __expf(-tot));
        gates[((size_t)(b * 16 + t)) * 2048 + n] = g;
    }
}

// ---------------- GEMM: C = A[M][K] * Bt[N][K]^T, bf16 in, fp32 acc ----------------

template <int EPI>
__global__ __launch_bounds__(256)
void gemm_bt_kernel(const unsigned short* __restrict__ A,
                    const unsigned short* __restrict__ Bt,
                    int M, int N, int K,
                    unsigned short* __restrict__ outQ,
                    unsigned short* __restrict__ outK,
                    unsigned short* __restrict__ outV,
                    float* __restrict__ outF) {
    __shared__ unsigned short As[128 * 32];
    __shared__ unsigned short Bs[128 * 32];
    const int lane = threadIdx.x & 63;
    const int w = threadIdx.x >> 6;
    const int wr = w >> 1, wc = w & 1;
    const int tm = blockIdx.y * 128;
    const int tn = blockIdx.x * 128;

    f32x4 acc[4][4];
#pragma unroll
    for (int m = 0; m < 4; m++)
#pragma unroll
        for (int n = 0; n < 4; n++) acc[m][n] = (f32x4){0.f, 0.f, 0.f, 0.f};

    const int sRow = lane >> 2;
    const int sCol = (lane & 3) * 8;

    const unsigned short* aFragBase = As + (wr * 64 + (lane & 15)) * 32 + (lane >> 4) * 8;
    const unsigned short* bFragBase = Bs + (wc * 64 + (lane & 15)) * 32 + (lane >> 4) * 8;

    for (int k0 = 0; k0 < K; k0 += 32) {
#pragma unroll
        for (int i = 0; i < 2; i++) {
            int chunk = w * 2 + i;
            int r = chunk * 16 + sRow;
            gload_lds16(A + (size_t)(tm + r) * K + k0 + sCol, (void*)(As + chunk * 512));
            gload_lds16(Bt + (size_t)(tn + r) * K + k0 + sCol, (void*)(Bs + chunk * 512));
        }
        __syncthreads();
        bf16x8 af[4], bg[4];
#pragma unroll
        for (int m = 0; m < 4; m++) af[m] = *(const bf16x8*)(aFragBase + m * 16 * 32);
#pragma unroll
        for (int n = 0; n < 4; n++) bg[n] = *(const bf16x8*)(bFragBase + n * 16 * 32);
#pragma unroll
        for (int m = 0; m < 4; m++)
#pragma unroll
            for (int n = 0; n < 4; n++)
                acc[m][n] = __builtin_amdgcn_mfma_f32_16x16x32_bf16(af[m], bg[n], acc[m][n], 0, 0, 0);
        __syncthreads();
    }

#pragma unroll
    for (int m = 0; m < 4; m++) {
        int row = tm + wr * 64 + m * 16 + (lane >> 4) * 4;
#pragma unroll
        for (int n = 0; n < 4; n++) {
            int col = tn + wc * 64 + n * 16 + (lane & 15);
#pragma unroll
            for (int r = 0; r < 4; r++) {
                float val = acc[m][n][r];
                int rr = row + r;
                if (EPI == 0) {
                    int which = col >> 10;
                    int h = (col >> 6) & 15;
                    int d = col & 63;
                    int b = rr >> 11;
                    int nn = rr & 2047;
                    size_t off = (((size_t)(b * 16 + h)) * 2048 + nn) * 64 + d;
                    if (which == 0)      outQ[off] = f2b(val * 0.125f);
                    else if (which == 1) outK[off] = f2b(val);
                    else                 outV[off] = f2b(val);
                } else {
                    outF[(size_t)rr * N + col] = val;
                }
            }
        }
    }
}

// ---------------- flash attention: softcap + causal + gate ----------------
// WORK-STEALING: 512 persistent blocks (R5's verified shape: 4 waves x 16
// q-rows) pull items (bh,qt) off a global atomic queue, ordered LONGEST-FIRST
// (item -> qt = 31 - item/32, bh = item%32). Any free CU takes the next item:
// balance is dispatch-policy-independent, backfill automatic. ~2 items/block.
// Output deterministic: items write disjoint q-rows with identical math.
// Inner loop = R5 verbatim: swapped-operand S^T = mfma(K,Q); softcap bounds
// |s|<=50 -> p=exp(s) fixed-max (purely additive, also what makes per-item
// independence trivial); P in regs via cvt_pk; V pre-permuted for 16B loads.

__global__ __launch_bounds__(256)
void attn_kernel(const unsigned short* __restrict__ Q,
                 const unsigned short* __restrict__ Kg,
                 const unsigned short* __restrict__ Vp,
                 const float* __restrict__ Gates,
                 unsigned short* __restrict__ Out,
                 unsigned int* __restrict__ ctr) {
    __shared__ unsigned int item_s;

    const int lane = threadIdx.x & 63;
    const int w = threadIdx.x >> 6;   // q-row wave 0..3
    const int g = lane >> 4;          // lane-group 0..3
    const int ql = lane & 15;         // q (and d) sub-index

    for (;;) {
        if (threadIdx.x == 0) item_s = atomicAdd(ctr, 1u);
        __syncthreads();
        const unsigned int item = item_s;
        __syncthreads();              // protect item_s before next overwrite
        if (item >= 1024u) break;

        const int qt = 31 - (int)(item >> 5);   // longest first
        const int bh = (int)(item & 31u);
        const int b = bh >> 4;
        const int h = bh & 15;

        const size_t headBase = (size_t)bh * 2048 * 64;

        // K fragment base (A-operand of QK^T): row k=ql, d-slots 8g..8g+7
        const unsigned short* Kfr = Kg + headBase + (size_t)ql * 64 + g * 8;
        // Vp fragment base (A-operand of PV): d-row ql (+16*nblk), slot g*16
        const unsigned short* Vfr = Vp + (size_t)bh * 131072 + (size_t)ql * 2048 + g * 16;

        const int qglob = qt * 64 + w * 16 + ql;
        const unsigned short* qp = Q + headBase + (size_t)qglob * 64 + g * 8;
        bf16x8 qa0 = *(const bf16x8*)qp;
        bf16x8 qa1 = *(const bf16x8*)(qp + 32);

        float lsum = 0.f;
        f32x4 o[4];
#pragma unroll
        for (int n = 0; n < 4; n++) o[n] = (f32x4){0.f, 0.f, 0.f, 0.f};

        bf16x8 kb[4][2];
#pragma unroll
        for (int n = 0; n < 4; n++) {
            const unsigned short* kp = Kfr + (size_t)(n * 16) * 64;
            kb[n][0] = *(const bf16x8*)kp;
            kb[n][1] = *(const bf16x8*)(kp + 32);
        }

        for (int jt = 0; jt <= qt; ++jt) {
            // S^T = K Q^T : lane holds S[k = jt*64+16n+4g+r][q = qglob]
            f32x4 s4[4];
#pragma unroll
            for (int n = 0; n < 4; n++) {
                f32x4 sv = (f32x4){0.f, 0.f, 0.f, 0.f};
                sv = __builtin_amdgcn_mfma_f32_16x16x32_bf16(kb[n][0], qa0, sv, 0, 0, 0);
                sv = __builtin_amdgcn_mfma_f32_16x16x32_bf16(kb[n][1], qa1, sv, 0, 0, 0);
                s4[n] = sv;
            }

            // prefetch next K tile (latency hides under softcap/exp VALU work)
            {
                int jn = (jt < qt) ? jt + 1 : 0;
#pragma unroll
                for (int n = 0; n < 4; n++) {
                    const unsigned short* kp = Kfr + (size_t)(jn * 64 + n * 16) * 64;
                    kb[n][0] = *(const bf16x8*)kp;
                    kb[n][1] = *(const bf16x8*)(kp + 32);
                }
            }

            // V loads for this tile (pre-permuted layout -> plain 16B loads)
            bf16x8 vA[4], vB[4];
            {
                const unsigned short* vbase = Vfr + jt * 64;
#pragma unroll
                for (int n = 0; n < 4; n++) {
                    const unsigned short* vp = vbase + (size_t)(n * 16) * 2048;
                    vA[n] = *(const bf16x8*)vp;
                    vB[n] = *(const bf16x8*)(vp + 8);
                }
            }

            // softcap + causal (branch-free; no-op off diagonal) + p = exp(s)
            float rs = 0.f;
#pragma unroll
            for (int n = 0; n < 4; n++) {
                int k0 = jt * 64 + n * 16 + 4 * g;
#pragma unroll
                for (int r = 0; r < 4; r++) {
                    float xx = s4[n][r];
                    float t = __builtin_amdgcn_exp2f(xx * 0.057707801635559964f);
                    float e2 = __builtin_fmaf(-144.26950408889634f,
                                              __builtin_amdgcn_rcpf(t + 1.f),
                                              72.13475204444817f);
                    if (k0 + r > qglob) e2 = -1e30f;
                    float p = __builtin_amdgcn_exp2f(e2);
                    s4[n][r] = p;
                    rs += p;
                }
            }
            lsum += rs;

            // P -> bf16 B-operands entirely in registers
            union PU { unsigned int u[4]; bf16x8 v; };
            PU p0, p1;
            p0.u[0] = cvtpk(s4[0][0], s4[0][1]);
            p0.u[1] = cvtpk(s4[0][2], s4[0][3]);
            p0.u[2] = cvtpk(s4[1][0], s4[1][1]);
            p0.u[3] = cvtpk(s4[1][2], s4[1][3]);
            p1.u[0] = cvtpk(s4[2][0], s4[2][1]);
            p1.u[1] = cvtpk(s4[2][2], s4[2][3]);
            p1.u[2] = cvtpk(s4[3][0], s4[3][1]);
            p1.u[3] = cvtpk(s4[3][2], s4[3][3]);

            // O^T += V^T P^T  (Vp layout matches P's k-slot permutation)
#pragma unroll
            for (int n = 0; n < 4; n++) {
                o[n] = __builtin_amdgcn_mfma_f32_16x16x32_bf16(vA[n], p0.v, o[n], 0, 0, 0);
                o[n] = __builtin_amdgcn_mfma_f32_16x16x32_bf16(vB[n], p1.v, o[n], 0, 0, 0);
            }
        }

        // epilogue: cross-lane l reduce (once), /l, *gate, pack 4 d per store
        float l = lsum;
        l += __shfl_xor(l, 16);
        l += __shfl_xor(l, 32);
        float gate = Gates[(size_t)bh * 2048 + qglob];
        float inv = gate / l;
        unsigned short* orow = Out + ((size_t)(b * 2048) + qglob) * 1024 + h * 64;
#pragma unroll
        for (int n = 0; n < 4; n++) {
            ushort4 st;
            st.x = f2b(o[n][0] * inv);
            st.y = f2b(o[n][1] * inv);
            st.z = f2b(o[n][2] * inv);
            st.w = f2b(o[n][3] * inv);
            *(ushort4*)(orow + n * 16 + 4 * g) = st;
        }
    }
}

// ---------------- launch ----------------

extern "C" void kernel_launch(void* const* d_in, const int* in_sizes, int n_in,
                              void* d_out, int out_size, void* d_ws, size_t ws_size,
                              hipStream_t stream) {
    const float* x       = (const float*)d_in[0];   // [2][2048][1024]
    const float* w_qkv   = (const float*)d_in[1];   // [1024][3072]
    const float* w_gates = (const float*)d_in[2];   // [1024][16]
    const float* w_out   = (const float*)d_in[3];   // [1024][1024]
    float* out = (float*)d_out;                     // [2][2048][1024]

    char* ws = (char*)d_ws;
    unsigned short* x_bf  = (unsigned short*)(ws);                      // 8 MB (reused as Vp later)
    unsigned short* wqkvT = (unsigned short*)(ws + ((size_t)8  << 20)); // 6 MB
    unsigned short* woutT = (unsigned short*)(ws + ((size_t)14 << 20)); // 2 MB
    unsigned short* qB    = (unsigned short*)(ws + ((size_t)16 << 20)); // 8 MB
    unsigned short* kB    = (unsigned short*)(ws + ((size_t)24 << 20)); // 8 MB
    unsigned short* vB    = (unsigned short*)(ws + ((size_t)32 << 20)); // 8 MB
    float*          gates = (float*)(ws + ((size_t)40 << 20));          // 256 KB
    unsigned int*   ctr   = (unsigned int*)(ws + ((size_t)40 << 20) + (512 << 10)); // 4 B
    unsigned short* attnO = (unsigned short*)(ws + ((size_t)41 << 20)); // 8 MB
    unsigned short* vP    = x_bf;                                       // reuse after gemm0

    cvt_x_kernel<<<dim3(4096), dim3(256), 0, stream>>>(x, x_bf);
    transpose_cvt<<<dim3(3072 / 32, 1024 / 32), dim3(32, 8), 0, stream>>>(w_qkv, wqkvT, 1024, 3072);
    transpose_cvt<<<dim3(1024 / 32, 1024 / 32), dim3(32, 8), 0, stream>>>(w_out, woutT, 1024, 1024);
    gates_kernel<<<dim3(4096), dim3(256), 0, stream>>>(x, w_gates, gates, ctr);

    gemm_bt_kernel<0><<<dim3(3072 / 128, 4096 / 128), dim3(256), 0, stream>>>(
        x_bf, wqkvT, 4096, 3072, 1024, qB, kB, vB, (float*)nullptr);

    vtrans_kernel<<<dim3(32, 32), dim3(256), 0, stream>>>(vB, vP);

    attn_kernel<<<dim3(512), dim3(256), 0, stream>>>(qB, kB, vP, gates, attnO, ctr);

    gemm_bt_kernel<1><<<dim3(1024 / 128, 4096 / 128), dim3(256), 0, stream>>>(
        attnO, woutT, 4096, 1024, 1024, nullptr, nullptr, nullptr, out);
}

// Round 12
// 171.112 us; speedup vs baseline: 1.5250x; 1.5250x over previous
//
#include <hip/hip_runtime.h>
#include <hip/hip_bf16.h>

typedef __bf16 bf16x8 __attribute__((ext_vector_type(8)));
typedef float f32x4 __attribute__((ext_vector_type(4)));

__device__ __forceinline__ unsigned short f2b(float f) {
    union { float f; unsigned int u; } v; v.f = f;
    unsigned int r = (v.u + 0x7FFFu + ((v.u >> 16) & 1u)) >> 16;
    return (unsigned short)r;
}

__device__ __forceinline__ unsigned int cvtpk(float lo, float hi) {
    unsigned int r;
    asm("v_cvt_pk_bf16_f32 %0, %1, %2" : "=v"(r) : "v"(lo), "v"(hi));
    return r;
}

__device__ __forceinline__ void gload_lds16(const void* g, void* l) {
    __builtin_amdgcn_global_load_lds((__attribute__((address_space(1))) void*)g,
                                     (__attribute__((address_space(3))) void*)l,
                                     16, 0, 0);
}

// ---------------- converts ----------------

__global__ __launch_bounds__(256) void cvt_x_kernel(const float* __restrict__ in,
                                                    unsigned short* __restrict__ out) {
    int i = (blockIdx.x * 256 + threadIdx.x) * 4;
    float4 f = *(const float4*)(in + i);
    ushort4 u;
    u.x = f2b(f.x); u.y = f2b(f.y); u.z = f2b(f.z); u.w = f2b(f.w);
    *(ushort4*)(out + i) = u;
}

// in: R x C fp32, out: C x R bf16 (transposed)
__global__ __launch_bounds__(256) void transpose_cvt(const float* __restrict__ in,
                                                     unsigned short* __restrict__ out,
                                                     int R, int C) {
    __shared__ float t[32][33];
    int c0 = blockIdx.x * 32, r0 = blockIdx.y * 32;
    int tx = threadIdx.x, ty = threadIdx.y;
#pragma unroll
    for (int i = 0; i < 4; i++)
        t[ty + i * 8][tx] = in[(size_t)(r0 + ty + i * 8) * C + c0 + tx];
    __syncthreads();
#pragma unroll
    for (int i = 0; i < 4; i++)
        out[(size_t)(c0 + ty + i * 8) * R + r0 + tx] = f2b(t[tx][ty + i * 8]);
}

// V [bh][n][64] bf16 -> Vp [bh][64][n'] bf16, k columns permuted per 64-tile:
// src col c = 16n + 4g + r  ->  dst col g*16 + n*4 + r
__global__ __launch_bounds__(256) void vtrans_kernel(const unsigned short* __restrict__ V,
                                                     unsigned short* __restrict__ Vp) {
    __shared__ unsigned short t[64][72];
    int bh = blockIdx.y, n0 = blockIdx.x * 64;
    int r = threadIdx.x >> 2, gd = threadIdx.x & 3;
    const unsigned short* src = V + ((size_t)bh * 2048 + n0 + r) * 64 + gd * 16;
    *(bf16x8*)&t[r][gd * 16]     = *(const bf16x8*)src;
    *(bf16x8*)&t[r][gd * 16 + 8] = *(const bf16x8*)(src + 8);
    __syncthreads();
    unsigned short tmp[16];
#pragma unroll
    for (int m = 0; m < 16; m++)
        tmp[m] = t[16 * (m >> 2) + 4 * gd + (m & 3)][r];   // inv-perm gather
    unsigned short* dst = Vp + ((size_t)bh * 64 + r) * 2048 + n0 + gd * 16;
    *(bf16x8*)dst       = *(const bf16x8*)tmp;
    *(bf16x8*)(dst + 8) = *(const bf16x8*)(tmp + 8);
}

// ---------------- gates: sigmoid(x @ w_gates) -> [b*16+h][n] ----------------

__global__ __launch_bounds__(256) void gates_kernel(const float* __restrict__ x,
                                                    const float* __restrict__ wg,
                                                    float* __restrict__ gates) {
    int row = blockIdx.x;            // 0..4095  (b*2048+n)
    int b = row >> 11, n = row & 2047;
    int t = threadIdx.x;
    int h = t & 15, fi = t >> 4;     // fi 0..15
    const float* xr = x + (size_t)row * 1024;
    float s = 0.f;
    for (int f = fi; f < 1024; f += 16)
        s += xr[f] * wg[f * 16 + h];
    __shared__ float red[16][17];
    red[fi][h] = s;
    __syncthreads();
    if (t < 16) {
        float tot = 0.f;
#pragma unroll
        for (int i = 0; i < 16; i++) tot += red[i][t];
        float g = 1.f / (1.f + __expf(-tot));
        gates[((size_t)(b * 16 + t)) * 2048 + n] = g;
    }
}

// ---------------- GEMM: C = A[M][K] * Bt[N][K]^T, bf16 in, fp32 acc ----------------

template <int EPI>
__global__ __launch_bounds__(256)
void gemm_bt_kernel(const unsigned short* __restrict__ A,
                    const unsigned short* __restrict__ Bt,
                    int M, int N, int K,
                    unsigned short* __restrict__ outQ,
                    unsigned short* __restrict__ outK,
                    unsigned short* __restrict__ outV,
                    float* __restrict__ outF) {
    __shared__ unsigned short As[128 * 32];
    __shared__ unsigned short Bs[128 * 32];
    const int lane = threadIdx.x & 63;
    const int w = threadIdx.x >> 6;
    const int wr = w >> 1, wc = w & 1;
    const int tm = blockIdx.y * 128;
    const int tn = blockIdx.x * 128;

    f32x4 acc[4][4];
#pragma unroll
    for (int m = 0; m < 4; m++)
#pragma unroll
        for (int n = 0; n < 4; n++) acc[m][n] = (f32x4){0.f, 0.f, 0.f, 0.f};

    const int sRow = lane >> 2;
    const int sCol = (lane & 3) * 8;

    const unsigned short* aFragBase = As + (wr * 64 + (lane & 15)) * 32 + (lane >> 4) * 8;
    const unsigned short* bFragBase = Bs + (wc * 64 + (lane & 15)) * 32 + (lane >> 4) * 8;

    for (int k0 = 0; k0 < K; k0 += 32) {
#pragma unroll
        for (int i = 0; i < 2; i++) {
            int chunk = w * 2 + i;
            int r = chunk * 16 + sRow;
            gload_lds16(A + (size_t)(tm + r) * K + k0 + sCol, (void*)(As + chunk * 512));
            gload_lds16(Bt + (size_t)(tn + r) * K + k0 + sCol, (void*)(Bs + chunk * 512));
        }
        __syncthreads();
        bf16x8 af[4], bg[4];
#pragma unroll
        for (int m = 0; m < 4; m++) af[m] = *(const bf16x8*)(aFragBase + m * 16 * 32);
#pragma unroll
        for (int n = 0; n < 4; n++) bg[n] = *(const bf16x8*)(bFragBase + n * 16 * 32);
#pragma unroll
        for (int m = 0; m < 4; m++)
#pragma unroll
            for (int n = 0; n < 4; n++)
                acc[m][n] = __builtin_amdgcn_mfma_f32_16x16x32_bf16(af[m], bg[n], acc[m][n], 0, 0, 0);
        __syncthreads();
    }

#pragma unroll
    for (int m = 0; m < 4; m++) {
        int row = tm + wr * 64 + m * 16 + (lane >> 4) * 4;
#pragma unroll
        for (int n = 0; n < 4; n++) {
            int col = tn + wc * 64 + n * 16 + (lane & 15);
#pragma unroll
            for (int r = 0; r < 4; r++) {
                float val = acc[m][n][r];
                int rr = row + r;
                if (EPI == 0) {
                    int which = col >> 10;
                    int h = (col >> 6) & 15;
                    int d = col & 63;
                    int b = rr >> 11;
                    int nn = rr & 2047;
                    size_t off = (((size_t)(b * 16 + h)) * 2048 + nn) * 64 + d;
                    if (which == 0)      outQ[off] = f2b(val * 0.125f);
                    else if (which == 1) outK[off] = f2b(val);
                    else                 outV[off] = f2b(val);
                } else {
                    outF[(size_t)rr * N + col] = val;
                }
            }
        }
    }
}

// ---------------- flash attention: softcap + causal + gate ----------------
// LDS-SHARED K/V: each wave previously pulled the full 16KB K+V tile through
// L1 per iteration (8 waves/CU x 16KB = 128KB/window @ ~64B/cyc = the observed
// ~2300-cycle floor -> L1-BW-bound; why R6-R11 scheduling changes were flat).
// Now the tile is staged ONCE per block into LDS via global_load_lds (each
// wave stages 1/4), double-buffered, one barrier/iter; waves read fragments
// via XOR-swizzled ds_read_b128 (chunk ^= row&7, pre-swizzled global source
// per the both-sides rule) -> 8-lane/quad BW floor, no 16-way conflicts.
// L1 traffic /4, LDS pipe (128B/cyc) carries distribution.
// 512 blocks = 32 bh x 16 pairs (q-tiles {p, 31-p} = 33 iters, balanced);
// 4 waves x 16 q-rows; swapped-operand S^T = mfma(K,Q); fixed-max softmax
// (softcap bounds |s|<=50); P in regs via cvt_pk; V pre-permuted (vtrans).

__global__ __launch_bounds__(256)
void attn_kernel(const unsigned short* __restrict__ Q,
                 const unsigned short* __restrict__ Kg,
                 const unsigned short* __restrict__ Vp,
                 const float* __restrict__ Gates,
                 unsigned short* __restrict__ Out) {
    __shared__ unsigned short lds[2][2][64][64];   // [dbuf][K|V][row][col] = 32KB

    const int lane = threadIdx.x & 63;
    const int w = threadIdx.x >> 6;   // wave 0..3 (q-rows AND staging quarter)
    const int g = lane >> 4;          // lane-group 0..3
    const int ql = lane & 15;         // q (and d) sub-index
    const int sw = ql & 7;            // read-swizzle key (row&7 of rows 16n+ql)
    const int srow = lane >> 3;       // staging: row within 8-row chunk
    const int sch = lane & 7;         // staging: LDS chunk this lane fills

    // XCD-chunked bijective swizzle: XCD i gets blocks [64i, 64i+64) = 4 heads
    const int wgid = (blockIdx.x & 7) * 64 + (blockIdx.x >> 3);
    const int bh = wgid >> 4;
    const int pair = wgid & 15;
    const int b = bh >> 4;
    const int h = bh & 15;

    const size_t headBase = (size_t)bh * 2048 * 64;
    const size_t vBase = (size_t)bh * 131072;

    // ds_read byte-chunk offsets (elements): K frag chunks g, g+4; V frag 2g, 2g+1
    const int koff0 = ((g) ^ sw) * 8;
    const int koff1 = ((g + 4) ^ sw) * 8;
    const int voff0 = ((2 * g) ^ sw) * 8;
    const int voff1 = ((2 * g + 1) ^ sw) * 8;

    for (int half = 0; half < 2; half++) {
        const int qt = half ? (31 - pair) : pair;
        const int qglob = qt * 64 + w * 16 + ql;

        const unsigned short* qp = Q + headBase + (size_t)qglob * 64 + g * 8;
        bf16x8 qa0 = *(const bf16x8*)qp;
        bf16x8 qa1 = *(const bf16x8*)(qp + 32);

        float lsum = 0.f;
        f32x4 o[4];
#pragma unroll
        for (int n = 0; n < 4; n++) o[n] = (f32x4){0.f, 0.f, 0.f, 0.f};

        // prologue: stage tile 0 -> buffer 0 (pre-swizzled global source)
#pragma unroll
        for (int i = 0; i < 2; i++) {
            int row = w * 16 + i * 8 + srow;
            int ch = sch ^ (row & 7);
            gload_lds16(Kg + headBase + (size_t)row * 64 + ch * 8,
                        (void*)&lds[0][0][w * 16 + i * 8][0]);
            gload_lds16(Vp + vBase + (size_t)row * 2048 + ch * 8,
                        (void*)&lds[0][1][w * 16 + i * 8][0]);
        }
        __syncthreads();

        for (int jt = 0; jt <= qt; ++jt) {
            const int bb = jt & 1;

            // stage next tile into the other buffer (latency hides under compute)
            if (jt < qt) {
                const int jn = jt + 1;
#pragma unroll
                for (int i = 0; i < 2; i++) {
                    int row = w * 16 + i * 8 + srow;
                    int ch = sch ^ (row & 7);
                    gload_lds16(Kg + headBase + (size_t)(jn * 64 + row) * 64 + ch * 8,
                                (void*)&lds[bb ^ 1][0][w * 16 + i * 8][0]);
                    gload_lds16(Vp + vBase + (size_t)row * 2048 + jn * 64 + ch * 8,
                                (void*)&lds[bb ^ 1][1][w * 16 + i * 8][0]);
                }
            }

            const unsigned short* KL = &lds[bb][0][0][0];
            const unsigned short* VL = &lds[bb][1][0][0];

            // S^T = K Q^T : lane holds S[k = jt*64+16n+4g+r][q = qglob]
            f32x4 s4[4];
#pragma unroll
            for (int n = 0; n < 4; n++) {
                const unsigned short* kr = KL + (16 * n + ql) * 64;
                bf16x8 k0 = *(const bf16x8*)(kr + koff0);
                bf16x8 k1 = *(const bf16x8*)(kr + koff1);
                f32x4 sv = (f32x4){0.f, 0.f, 0.f, 0.f};
                sv = __builtin_amdgcn_mfma_f32_16x16x32_bf16(k0, qa0, sv, 0, 0, 0);
                sv = __builtin_amdgcn_mfma_f32_16x16x32_bf16(k1, qa1, sv, 0, 0, 0);
                s4[n] = sv;
            }

            // softcap + causal (branch-free) + p = exp(s) with fixed max
            float rs = 0.f;
#pragma unroll
            for (int n = 0; n < 4; n++) {
                int k0c = jt * 64 + n * 16 + 4 * g;
#pragma unroll
                for (int r = 0; r < 4; r++) {
                    float xx = s4[n][r];
                    float t = __builtin_amdgcn_exp2f(xx * 0.057707801635559964f);
                    float e2 = __builtin_fmaf(-144.26950408889634f,
                                              __builtin_amdgcn_rcpf(t + 1.f),
                                              72.13475204444817f);
                    if (k0c + r > qglob) e2 = -1e30f;
                    float p = __builtin_amdgcn_exp2f(e2);
                    s4[n][r] = p;
                    rs += p;
                }
            }
            lsum += rs;

            // P -> bf16 B-operands entirely in registers
            union PU { unsigned int u[4]; bf16x8 v; };
            PU p0, p1;
            p0.u[0] = cvtpk(s4[0][0], s4[0][1]);
            p0.u[1] = cvtpk(s4[0][2], s4[0][3]);
            p0.u[2] = cvtpk(s4[1][0], s4[1][1]);
            p0.u[3] = cvtpk(s4[1][2], s4[1][3]);
            p1.u[0] = cvtpk(s4[2][0], s4[2][1]);
            p1.u[1] = cvtpk(s4[2][2], s4[2][3]);
            p1.u[2] = cvtpk(s4[3][0], s4[3][1]);
            p1.u[3] = cvtpk(s4[3][2], s4[3][3]);

            // O^T += V^T P^T  (Vp layout matches P's k-slot permutation)
#pragma unroll
            for (int n = 0; n < 4; n++) {
                const unsigned short* vr = VL + (16 * n + ql) * 64;
                bf16x8 vA = *(const bf16x8*)(vr + voff0);
                bf16x8 vB = *(const bf16x8*)(vr + voff1);
                o[n] = __builtin_amdgcn_mfma_f32_16x16x32_bf16(vA, p0.v, o[n], 0, 0, 0);
                o[n] = __builtin_amdgcn_mfma_f32_16x16x32_bf16(vB, p1.v, o[n], 0, 0, 0);
            }

            __syncthreads();   // stage(jt+1) drained; all reads of bb done
        }

        // epilogue: cross-lane l reduce (once), /l, *gate, pack 4 d per store
        float l = lsum;
        l += __shfl_xor(l, 16);
        l += __shfl_xor(l, 32);
        float gate = Gates[(size_t)bh * 2048 + qglob];
        float inv = gate / l;
        unsigned short* orow = Out + ((size_t)(b * 2048) + qglob) * 1024 + h * 64;
#pragma unroll
        for (int n = 0; n < 4; n++) {
            ushort4 st;
            st.x = f2b(o[n][0] * inv);
            st.y = f2b(o[n][1] * inv);
            st.z = f2b(o[n][2] * inv);
            st.w = f2b(o[n][3] * inv);
            *(ushort4*)(orow + n * 16 + 4 * g) = st;
        }
    }
}

// ---------------- launch ----------------

extern "C" void kernel_launch(void* const* d_in, const int* in_sizes, int n_in,
                              void* d_out, int out_size, void* d_ws, size_t ws_size,
                              hipStream_t stream) {
    const float* x       = (const float*)d_in[0];   // [2][2048][1024]
    const float* w_qkv   = (const float*)d_in[1];   // [1024][3072]
    const float* w_gates = (const float*)d_in[2];   // [1024][16]
    const float* w_out   = (const float*)d_in[3];   // [1024][1024]
    float* out = (float*)d_out;                     // [2][2048][1024]

    char* ws = (char*)d_ws;
    unsigned short* x_bf  = (unsigned short*)(ws);                      // 8 MB (reused as Vp later)
    unsigned short* wqkvT = (unsigned short*)(ws + ((size_t)8  << 20)); // 6 MB
    unsigned short* woutT = (unsigned short*)(ws + ((size_t)14 << 20)); // 2 MB
    unsigned short* qB    = (unsigned short*)(ws + ((size_t)16 << 20)); // 8 MB
    unsigned short* kB    = (unsigned short*)(ws + ((size_t)24 << 20)); // 8 MB
    unsigned short* vB    = (unsigned short*)(ws + ((size_t)32 << 20)); // 8 MB
    float*          gates = (float*)(ws + ((size_t)40 << 20));          // 256 KB
    unsigned short* attnO = (unsigned short*)(ws + ((size_t)41 << 20)); // 8 MB
    unsigned short* vP    = x_bf;                                       // reuse after gemm0

    cvt_x_kernel<<<dim3(4096), dim3(256), 0, stream>>>(x, x_bf);
    transpose_cvt<<<dim3(3072 / 32, 1024 / 32), dim3(32, 8), 0, stream>>>(w_qkv, wqkvT, 1024, 3072);
    transpose_cvt<<<dim3(1024 / 32, 1024 / 32), dim3(32, 8), 0, stream>>>(w_out, woutT, 1024, 1024);
    gates_kernel<<<dim3(4096), dim3(256), 0, stream>>>(x, w_gates, gates);

    gemm_bt_kernel<0><<<dim3(3072 / 128, 4096 / 128), dim3(256), 0, stream>>>(
        x_bf, wqkvT, 4096, 3072, 1024, qB, kB, vB, (float*)nullptr);

    vtrans_kernel<<<dim3(32, 32), dim3(256), 0, stream>>>(vB, vP);

    attn_kernel<<<dim3(512), dim3(256), 0, stream>>>(qB, kB, vP, gates, attnO);

    gemm_bt_kernel<1><<<dim3(1024 / 128, 4096 / 128), dim3(256), 0, stream>>>(
        attnO, woutT, 4096, 1024, 1024, nullptr, nullptr, nullptr, out);
}

// Round 14
// 161.609 us; speedup vs baseline: 1.6147x; 1.0588x over previous
//
#include <hip/hip_runtime.h>
#include <hip/hip_bf16.h>

typedef __bf16 bf16x8 __attribute__((ext_vector_type(8)));
typedef float f32x4 __attribute__((ext_vector_type(4)));

__device__ __forceinline__ unsigned short f2b(float f) {
    union { float f; unsigned int u; } v; v.f = f;
    unsigned int r = (v.u + 0x7FFFu + ((v.u >> 16) & 1u)) >> 16;
    return (unsigned short)r;
}

__device__ __forceinline__ unsigned int cvtpk(float lo, float hi) {
    unsigned int r;
    asm("v_cvt_pk_bf16_f32 %0, %1, %2" : "=v"(r) : "v"(lo), "v"(hi));
    return r;
}

__device__ __forceinline__ void gload_lds16(const void* g, void* l) {
    __builtin_amdgcn_global_load_lds((__attribute__((address_space(1))) void*)g,
                                     (__attribute__((address_space(3))) void*)l,
                                     16, 0, 0);
}

// ---------------- converts ----------------

__global__ __launch_bounds__(256) void cvt_x_kernel(const float* __restrict__ in,
                                                    unsigned short* __restrict__ out) {
    int i = (blockIdx.x * 256 + threadIdx.x) * 4;
    float4 f = *(const float4*)(in + i);
    ushort4 u;
    u.x = f2b(f.x); u.y = f2b(f.y); u.z = f2b(f.z); u.w = f2b(f.w);
    *(ushort4*)(out + i) = u;
}

// in: R x C fp32, out: C x R bf16 (transposed)
__global__ __launch_bounds__(256) void transpose_cvt(const float* __restrict__ in,
                                                     unsigned short* __restrict__ out,
                                                     int R, int C) {
    __shared__ float t[32][33];
    int c0 = blockIdx.x * 32, r0 = blockIdx.y * 32;
    int tx = threadIdx.x, ty = threadIdx.y;
#pragma unroll
    for (int i = 0; i < 4; i++)
        t[ty + i * 8][tx] = in[(size_t)(r0 + ty + i * 8) * C + c0 + tx];
    __syncthreads();
#pragma unroll
    for (int i = 0; i < 4; i++)
        out[(size_t)(c0 + ty + i * 8) * R + r0 + tx] = f2b(t[tx][ty + i * 8]);
}

// ---------------- gates: sigmoid(x @ w_gates) -> [b*16+h][n] ----------------

__global__ __launch_bounds__(256) void gates_kernel(const float* __restrict__ x,
                                                    const float* __restrict__ wg,
                                                    float* __restrict__ gates) {
    int row = blockIdx.x;            // 0..4095  (b*2048+n)
    int b = row >> 11, n = row & 2047;
    int t = threadIdx.x;
    int h = t & 15, fi = t >> 4;     // fi 0..15
    const float* xr = x + (size_t)row * 1024;
    float s = 0.f;
    for (int f = fi; f < 1024; f += 16)
        s += xr[f] * wg[f * 16 + h];
    __shared__ float red[16][17];
    red[fi][h] = s;
    __syncthreads();
    if (t < 16) {
        float tot = 0.f;
#pragma unroll
        for (int i = 0; i < 16; i++) tot += red[i][t];
        float g = 1.f / (1.f + __expf(-tot));
        gates[((size_t)(b * 16 + t)) * 2048 + n] = g;
    }
}

// ---------------- GEMM: C = A[M][K] * Bt[N][K]^T, bf16 in, fp32 acc ----------------
// EPI 0: Q (x0.125) and K as [b][h][n][d] bf16; V written DIRECTLY in the attn
// kernel's layout Vp[bh][d][permC(nn)] where rows are PLAIN d and the k-slot
// permutation applies to the KV COLUMN index:
//   permC(nn) = (nn&~63) + ((nn>>2)&3)*16 + ((nn>>4)&3)*4 + (nn&3)
// (R13 bug: permuted d instead of nn). Fragment rows nn..nn+3 (nn%4==0) map to
// permC(nn)..permC(nn)+3 -> packed ushort4 store stays valid and 8B-aligned.
// EPI 1: fp32 out [M][N].

template <int EPI>
__global__ __launch_bounds__(256)
void gemm_bt_kernel(const unsigned short* __restrict__ A,
                    const unsigned short* __restrict__ Bt,
                    int M, int N, int K,
                    unsigned short* __restrict__ outQ,
                    unsigned short* __restrict__ outK,
                    unsigned short* __restrict__ outV,
                    float* __restrict__ outF) {
    __shared__ unsigned short As[128 * 32];
    __shared__ unsigned short Bs[128 * 32];
    const int lane = threadIdx.x & 63;
    const int w = threadIdx.x >> 6;
    const int wr = w >> 1, wc = w & 1;
    const int tm = blockIdx.y * 128;
    const int tn = blockIdx.x * 128;

    f32x4 acc[4][4];
#pragma unroll
    for (int m = 0; m < 4; m++)
#pragma unroll
        for (int n = 0; n < 4; n++) acc[m][n] = (f32x4){0.f, 0.f, 0.f, 0.f};

    const int sRow = lane >> 2;
    const int sCol = (lane & 3) * 8;

    const unsigned short* aFragBase = As + (wr * 64 + (lane & 15)) * 32 + (lane >> 4) * 8;
    const unsigned short* bFragBase = Bs + (wc * 64 + (lane & 15)) * 32 + (lane >> 4) * 8;

    for (int k0 = 0; k0 < K; k0 += 32) {
#pragma unroll
        for (int i = 0; i < 2; i++) {
            int chunk = w * 2 + i;
            int r = chunk * 16 + sRow;
            gload_lds16(A + (size_t)(tm + r) * K + k0 + sCol, (void*)(As + chunk * 512));
            gload_lds16(Bt + (size_t)(tn + r) * K + k0 + sCol, (void*)(Bs + chunk * 512));
        }
        __syncthreads();
        bf16x8 af[4], bg[4];
#pragma unroll
        for (int m = 0; m < 4; m++) af[m] = *(const bf16x8*)(aFragBase + m * 16 * 32);
#pragma unroll
        for (int n = 0; n < 4; n++) bg[n] = *(const bf16x8*)(bFragBase + n * 16 * 32);
#pragma unroll
        for (int m = 0; m < 4; m++)
#pragma unroll
            for (int n = 0; n < 4; n++)
                acc[m][n] = __builtin_amdgcn_mfma_f32_16x16x32_bf16(af[m], bg[n], acc[m][n], 0, 0, 0);
        __syncthreads();
    }

#pragma unroll
    for (int m = 0; m < 4; m++) {
        int row = tm + wr * 64 + m * 16 + (lane >> 4) * 4;
#pragma unroll
        for (int n = 0; n < 4; n++) {
            int col = tn + wc * 64 + n * 16 + (lane & 15);
            if (EPI == 0) {
                int which = col >> 10;           // uniform per block (128 | 1024)
                int hh = (col >> 6) & 15;
                int d = col & 63;
                int b0 = row >> 11;              // rows don't cross b (128 | 2048)
                int nn = row & 2047;             // nn % 4 == 0
                size_t bh = (size_t)(b0 * 16 + hh);
                if (which == 2) {
                    int i6 = nn & 63;
                    int pc = (nn & ~63) + ((i6 >> 2) & 3) * 16 + ((i6 >> 4) & 3) * 4;
                    ushort4 st;
                    st.x = f2b(acc[m][n][0]);
                    st.y = f2b(acc[m][n][1]);
                    st.z = f2b(acc[m][n][2]);
                    st.w = f2b(acc[m][n][3]);
                    *(ushort4*)(outV + bh * 131072 + (size_t)d * 2048 + pc) = st;
                } else if (which == 0) {
                    size_t off = (bh * 2048 + nn) * 64 + d;
#pragma unroll
                    for (int r = 0; r < 4; r++)
                        outQ[off + (size_t)r * 64] = f2b(acc[m][n][r] * 0.125f);
                } else {
                    size_t off = (bh * 2048 + nn) * 64 + d;
#pragma unroll
                    for (int r = 0; r < 4; r++)
                        outK[off + (size_t)r * 64] = f2b(acc[m][n][r]);
                }
            } else {
#pragma unroll
                for (int r = 0; r < 4; r++)
                    outF[(size_t)(row + r) * N + col] = acc[m][n][r];
            }
        }
    }
}

// ---------------- flash attention: softcap + causal + gate ----------------
// LDS-shared K/V (R12, confirmed L1-BW fix: 127->52us), double-buffered,
// XOR-swizzled ds_read_b128. Softcap via 5th-order odd tanh series:
// 50*tanh(x/50)*log2e = (x*log2e)*(1 + c1*x^2 + c2*x^4) -- 1 SFU/elem
// (the final exp2) instead of 3. Truncation <= 9e-5 in tanh for |x|<=20.
// 512 blocks = 32 bh x 16 pairs (q-tiles {p,31-p} = 33 iters, balanced);
// 4 waves x 16 q-rows; swapped-operand S^T = mfma(K,Q); fixed-max softmax
// (softcap bounds |s|<=50); P in regs via cvt_pk; V pre-permuted (by gemm0).

__global__ __launch_bounds__(256)
void attn_kernel(const unsigned short* __restrict__ Q,
                 const unsigned short* __restrict__ Kg,
                 const unsigned short* __restrict__ Vp,
                 const float* __restrict__ Gates,
                 unsigned short* __restrict__ Out) {
    __shared__ unsigned short lds[2][2][64][64];   // [dbuf][K|V][row][col] = 32KB

    const int lane = threadIdx.x & 63;
    const int w = threadIdx.x >> 6;   // wave 0..3 (q-rows AND staging quarter)
    const int g = lane >> 4;          // lane-group 0..3
    const int ql = lane & 15;         // q (and d) sub-index
    const int sw = ql & 7;            // read-swizzle key
    const int srow = lane >> 3;       // staging: row within 8-row chunk
    const int sch = lane & 7;         // staging: LDS chunk this lane fills

    // XCD-chunked bijective swizzle: XCD i gets blocks [64i, 64i+64) = 4 heads
    const int wgid = (blockIdx.x & 7) * 64 + (blockIdx.x >> 3);
    const int bh = wgid >> 4;
    const int pair = wgid & 15;
    const int b = bh >> 4;
    const int h = bh & 15;

    const size_t headBase = (size_t)bh * 2048 * 64;
    const size_t vBase = (size_t)bh * 131072;

    const int koff0 = ((g) ^ sw) * 8;
    const int koff1 = ((g + 4) ^ sw) * 8;
    const int voff0 = ((2 * g) ^ sw) * 8;
    const int voff1 = ((2 * g + 1) ^ sw) * 8;

    // softcap-in-exp2 poly: e2 = (x*log2e)*(1 + c1*x^2 + c2*x^4)
    const float C1 = -1.3333333333e-4f;      // -(1/3)/2500
    const float C2 = 2.1333333333e-8f;       // (2/15)/2500^2
    const float LOG2E = 1.4426950408889634f;

    for (int half = 0; half < 2; half++) {
        const int qt = half ? (31 - pair) : pair;
        const int qglob = qt * 64 + w * 16 + ql;

        const unsigned short* qp = Q + headBase + (size_t)qglob * 64 + g * 8;
        bf16x8 qa0 = *(const bf16x8*)qp;
        bf16x8 qa1 = *(const bf16x8*)(qp + 32);

        float lsum = 0.f;
        f32x4 o[4];
#pragma unroll
        for (int n = 0; n < 4; n++) o[n] = (f32x4){0.f, 0.f, 0.f, 0.f};

        // prologue: stage tile 0 -> buffer 0 (pre-swizzled global source)
#pragma unroll
        for (int i = 0; i < 2; i++) {
            int row = w * 16 + i * 8 + srow;
            int ch = sch ^ (row & 7);
            gload_lds16(Kg + headBase + (size_t)row * 64 + ch * 8,
                        (void*)&lds[0][0][w * 16 + i * 8][0]);
            gload_lds16(Vp + vBase + (size_t)row * 2048 + ch * 8,
                        (void*)&lds[0][1][w * 16 + i * 8][0]);
        }
        __syncthreads();

        for (int jt = 0; jt <= qt; ++jt) {
            const int bb = jt & 1;

            // stage next tile into the other buffer (hides under compute)
            if (jt < qt) {
                const int jn = jt + 1;
#pragma unroll
                for (int i = 0; i < 2; i++) {
                    int row = w * 16 + i * 8 + srow;
                    int ch = sch ^ (row & 7);
                    gload_lds16(Kg + headBase + (size_t)(jn * 64 + row) * 64 + ch * 8,
                                (void*)&lds[bb ^ 1][0][w * 16 + i * 8][0]);
                    gload_lds16(Vp + vBase + (size_t)row * 2048 + jn * 64 + ch * 8,
                                (void*)&lds[bb ^ 1][1][w * 16 + i * 8][0]);
                }
            }

            const unsigned short* KL = &lds[bb][0][0][0];
            const unsigned short* VL = &lds[bb][1][0][0];

            // S^T = K Q^T : lane holds S[k = jt*64+16n+4g+r][q = qglob]
            f32x4 s4[4];
#pragma unroll
            for (int n = 0; n < 4; n++) {
                const unsigned short* kr = KL + (16 * n + ql) * 64;
                bf16x8 k0 = *(const bf16x8*)(kr + koff0);
                bf16x8 k1 = *(const bf16x8*)(kr + koff1);
                f32x4 sv = (f32x4){0.f, 0.f, 0.f, 0.f};
                sv = __builtin_amdgcn_mfma_f32_16x16x32_bf16(k0, qa0, sv, 0, 0, 0);
                sv = __builtin_amdgcn_mfma_f32_16x16x32_bf16(k1, qa1, sv, 0, 0, 0);
                s4[n] = sv;
            }

            // softcap (poly, 1 SFU) + causal (branch-free) + p = exp2(e2)
            float rs = 0.f;
#pragma unroll
            for (int n = 0; n < 4; n++) {
                int k0c = jt * 64 + n * 16 + 4 * g;
#pragma unroll
                for (int r = 0; r < 4; r++) {
                    float xx = s4[n][r];
                    float x2 = xx * xx;
                    float pol = __builtin_fmaf(x2, __builtin_fmaf(x2, C2, C1), 1.f);
                    float e2 = (xx * LOG2E) * pol;
                    if (k0c + r > qglob) e2 = -1e30f;
                    float p = __builtin_amdgcn_exp2f(e2);
                    s4[n][r] = p;
                    rs += p;
                }
            }
            lsum += rs;

            // P -> bf16 B-operands entirely in registers
            union PU { unsigned int u[4]; bf16x8 v; };
            PU p0, p1;
            p0.u[0] = cvtpk(s4[0][0], s4[0][1]);
            p0.u[1] = cvtpk(s4[0][2], s4[0][3]);
            p0.u[2] = cvtpk(s4[1][0], s4[1][1]);
            p0.u[3] = cvtpk(s4[1][2], s4[1][3]);
            p1.u[0] = cvtpk(s4[2][0], s4[2][1]);
            p1.u[1] = cvtpk(s4[2][2], s4[2][3]);
            p1.u[2] = cvtpk(s4[3][0], s4[3][1]);
            p1.u[3] = cvtpk(s4[3][2], s4[3][3]);

            // O^T += V^T P^T  (Vp layout matches P's k-slot permutation)
#pragma unroll
            for (int n = 0; n < 4; n++) {
                const unsigned short* vr = VL + (16 * n + ql) * 64;
                bf16x8 vA = *(const bf16x8*)(vr + voff0);
                bf16x8 vB = *(const bf16x8*)(vr + voff1);
                o[n] = __builtin_amdgcn_mfma_f32_16x16x32_bf16(vA, p0.v, o[n], 0, 0, 0);
                o[n] = __builtin_amdgcn_mfma_f32_16x16x32_bf16(vB, p1.v, o[n], 0, 0, 0);
            }

            __syncthreads();   // stage(jt+1) drained; all reads of bb done
        }

        // epilogue: cross-lane l reduce (once), /l, *gate, pack 4 d per store
        float l = lsum;
        l += __shfl_xor(l, 16);
        l += __shfl_xor(l, 32);
        float gate = Gates[(size_t)bh * 2048 + qglob];
        float inv = gate / l;
        unsigned short* orow = Out + ((size_t)(b * 2048) + qglob) * 1024 + h * 64;
#pragma unroll
        for (int n = 0; n < 4; n++) {
            ushort4 st;
            st.x = f2b(o[n][0] * inv);
            st.y = f2b(o[n][1] * inv);
            st.z = f2b(o[n][2] * inv);
            st.w = f2b(o[n][3] * inv);
            *(ushort4*)(orow + n * 16 + 4 * g) = st;
        }
    }
}

// ---------------- launch ----------------

extern "C" void kernel_launch(void* const* d_in, const int* in_sizes, int n_in,
                              void* d_out, int out_size, void* d_ws, size_t ws_size,
                              hipStream_t stream) {
    const float* x       = (const float*)d_in[0];   // [2][2048][1024]
    const float* w_qkv   = (const float*)d_in[1];   // [1024][3072]
    const float* w_gates = (const float*)d_in[2];   // [1024][16]
    const float* w_out   = (const float*)d_in[3];   // [1024][1024]
    float* out = (float*)d_out;                     // [2][2048][1024]

    char* ws = (char*)d_ws;
    unsigned short* x_bf  = (unsigned short*)(ws);                      // 8 MB
    unsigned short* wqkvT = (unsigned short*)(ws + ((size_t)8  << 20)); // 6 MB
    unsigned short* woutT = (unsigned short*)(ws + ((size_t)14 << 20)); // 2 MB
    unsigned short* qB    = (unsigned short*)(ws + ((size_t)16 << 20)); // 8 MB
    unsigned short* kB    = (unsigned short*)(ws + ((size_t)24 << 20)); // 8 MB
    unsigned short* vP    = (unsigned short*)(ws + ((size_t)32 << 20)); // 8 MB (permuted V, written by gemm0)
    float*          gates = (float*)(ws + ((size_t)40 << 20));          // 256 KB
    unsigned short* attnO = (unsigned short*)(ws + ((size_t)41 << 20)); // 8 MB

    cvt_x_kernel<<<dim3(4096), dim3(256), 0, stream>>>(x, x_bf);
    transpose_cvt<<<dim3(3072 / 32, 1024 / 32), dim3(32, 8), 0, stream>>>(w_qkv, wqkvT, 1024, 3072);
    transpose_cvt<<<dim3(1024 / 32, 1024 / 32), dim3(32, 8), 0, stream>>>(w_out, woutT, 1024, 1024);
    gates_kernel<<<dim3(4096), dim3(256), 0, stream>>>(x, w_gates, gates);

    gemm_bt_kernel<0><<<dim3(3072 / 128, 4096 / 128), dim3(256), 0, stream>>>(
        x_bf, wqkvT, 4096, 3072, 1024, qB, kB, vP, (float*)nullptr);

    attn_kernel<<<dim3(512), dim3(256), 0, stream>>>(qB, kB, vP, gates, attnO);

    gemm_bt_kernel<1><<<dim3(1024 / 128, 4096 / 128), dim3(256), 0, stream>>>(
        attnO, woutT, 4096, 1024, 1024, nullptr, nullptr, nullptr, out);
}

// Round 15
// 145.497 us; speedup vs baseline: 1.7935x; 1.1107x over previous
//
#include <hip/hip_runtime.h>
#include <hip/hip_bf16.h>

typedef __bf16 bf16x8 __attribute__((ext_vector_type(8)));
typedef float f32x4 __attribute__((ext_vector_type(4)));

__device__ __forceinline__ unsigned short f2b(float f) {
    union { float f; unsigned int u; } v; v.f = f;
    unsigned int r = (v.u + 0x7FFFu + ((v.u >> 16) & 1u)) >> 16;
    return (unsigned short)r;
}

__device__ __forceinline__ unsigned int cvtpk(float lo, float hi) {
    unsigned int r;
    asm("v_cvt_pk_bf16_f32 %0, %1, %2" : "=v"(r) : "v"(lo), "v"(hi));
    return r;
}

__device__ __forceinline__ void gload_lds16(const void* g, void* l) {
    __builtin_amdgcn_global_load_lds((__attribute__((address_space(1))) void*)g,
                                     (__attribute__((address_space(3))) void*)l,
                                     16, 0, 0);
}

// ---- fused convert + gates: x -> x_bf (bf16), gates = sigmoid(x @ wg) ----

__global__ __launch_bounds__(256) void cvtgates_kernel(const float* __restrict__ x,
                                                       const float* __restrict__ wg,
                                                       unsigned short* __restrict__ xb,
                                                       float* __restrict__ gates) {
    __shared__ float xs[1024];
    __shared__ float red[16][17];
    const int row = blockIdx.x;          // b*2048+n
    const int t = threadIdx.x;
    const float* xr = x + (size_t)row * 1024;
    float4 f = *(const float4*)(xr + t * 4);
    *(float4*)(xs + t * 4) = f;
    ushort4 u;
    u.x = f2b(f.x); u.y = f2b(f.y); u.z = f2b(f.z); u.w = f2b(f.w);
    *(ushort4*)(xb + (size_t)row * 1024 + t * 4) = u;
    __syncthreads();
    const int h = t & 15, fi = t >> 4;
    float s = 0.f;
    for (int ff = fi; ff < 1024; ff += 16)
        s += xs[ff] * wg[ff * 16 + h];
    red[fi][h] = s;
    __syncthreads();
    if (t < 16) {
        float tot = 0.f;
#pragma unroll
        for (int i = 0; i < 16; i++) tot += red[i][t];
        int b = row >> 11, n = row & 2047;
        gates[((size_t)(b * 16 + t)) * 2048 + n] = 1.f / (1.f + __expf(-tot));
    }
}

// ---- merged weight transposes: w_qkv (1024x3072) and w_out (1024x1024) ----

__global__ __launch_bounds__(256) void transpose_cvt2(const float* __restrict__ wq,
                                                      const float* __restrict__ wo,
                                                      unsigned short* __restrict__ outq,
                                                      unsigned short* __restrict__ outo) {
    __shared__ float t[32][33];
    const int bx = blockIdx.x;
    const float* in;
    unsigned short* out;
    int C, c0;
    if (bx < 96) { in = wq; out = outq; C = 3072; c0 = bx * 32; }
    else         { in = wo; out = outo; C = 1024; c0 = (bx - 96) * 32; }
    const int r0 = blockIdx.y * 32;      // R = 1024
    const int tx = threadIdx.x, ty = threadIdx.y;
#pragma unroll
    for (int i = 0; i < 4; i++)
        t[ty + i * 8][tx] = in[(size_t)(r0 + ty + i * 8) * C + c0 + tx];
    __syncthreads();
#pragma unroll
    for (int i = 0; i < 4; i++)
        out[(size_t)(c0 + ty + i * 8) * 1024 + r0 + tx] = f2b(t[tx][ty + i * 8]);
}

// ---------------- GEMM: C = A[M][K] * Bt[N][K]^T, bf16 in, fp32 acc ----------------
// BK=64: two 32-chunks staged per barrier interval (halves barrier-drain count).
// EPI 0: Q (x0.125), K as [b][h][n][d]; V directly in Vp[bh][d][permC(nn)],
//   permC(nn) = (nn&~63) + ((nn>>2)&3)*16 + ((nn>>4)&3)*4 + (nn&3).
// EPI 1: fp32 out [M][N].

template <int EPI>
__global__ __launch_bounds__(256)
void gemm_bt_kernel(const unsigned short* __restrict__ A,
                    const unsigned short* __restrict__ Bt,
                    int M, int N, int K,
                    unsigned short* __restrict__ outQ,
                    unsigned short* __restrict__ outK,
                    unsigned short* __restrict__ outV,
                    float* __restrict__ outF) {
    __shared__ unsigned short As[2][128 * 32];
    __shared__ unsigned short Bs[2][128 * 32];
    const int lane = threadIdx.x & 63;
    const int w = threadIdx.x >> 6;
    const int wr = w >> 1, wc = w & 1;
    const int tm = blockIdx.y * 128;
    const int tn = blockIdx.x * 128;

    f32x4 acc[4][4];
#pragma unroll
    for (int m = 0; m < 4; m++)
#pragma unroll
        for (int n = 0; n < 4; n++) acc[m][n] = (f32x4){0.f, 0.f, 0.f, 0.f};

    const int sRow = lane >> 2;
    const int sCol = (lane & 3) * 8;
    const int fragA = (wr * 64 + (lane & 15)) * 32 + (lane >> 4) * 8;
    const int fragB = (wc * 64 + (lane & 15)) * 32 + (lane >> 4) * 8;

    for (int k0 = 0; k0 < K; k0 += 64) {
#pragma unroll
        for (int c = 0; c < 2; c++)
#pragma unroll
            for (int i = 0; i < 2; i++) {
                int chunk = w * 2 + i;
                int r = chunk * 16 + sRow;
                gload_lds16(A + (size_t)(tm + r) * K + k0 + c * 32 + sCol,
                            (void*)(As[c] + chunk * 512));
                gload_lds16(Bt + (size_t)(tn + r) * K + k0 + c * 32 + sCol,
                            (void*)(Bs[c] + chunk * 512));
            }
        __syncthreads();
#pragma unroll
        for (int c = 0; c < 2; c++) {
            bf16x8 af[4], bg[4];
#pragma unroll
            for (int m = 0; m < 4; m++) af[m] = *(const bf16x8*)(As[c] + fragA + m * 16 * 32);
#pragma unroll
            for (int n = 0; n < 4; n++) bg[n] = *(const bf16x8*)(Bs[c] + fragB + n * 16 * 32);
#pragma unroll
            for (int m = 0; m < 4; m++)
#pragma unroll
                for (int n = 0; n < 4; n++)
                    acc[m][n] = __builtin_amdgcn_mfma_f32_16x16x32_bf16(af[m], bg[n], acc[m][n], 0, 0, 0);
        }
        __syncthreads();
    }

#pragma unroll
    for (int m = 0; m < 4; m++) {
        int row = tm + wr * 64 + m * 16 + (lane >> 4) * 4;
#pragma unroll
        for (int n = 0; n < 4; n++) {
            int col = tn + wc * 64 + n * 16 + (lane & 15);
            if (EPI == 0) {
                int which = col >> 10;
                int hh = (col >> 6) & 15;
                int d = col & 63;
                int b0 = row >> 11;
                int nn = row & 2047;             // nn % 4 == 0
                size_t bh = (size_t)(b0 * 16 + hh);
                if (which == 2) {
                    int i6 = nn & 63;
                    int pc = (nn & ~63) + ((i6 >> 2) & 3) * 16 + ((i6 >> 4) & 3) * 4;
                    ushort4 st;
                    st.x = f2b(acc[m][n][0]);
                    st.y = f2b(acc[m][n][1]);
                    st.z = f2b(acc[m][n][2]);
                    st.w = f2b(acc[m][n][3]);
                    *(ushort4*)(outV + bh * 131072 + (size_t)d * 2048 + pc) = st;
                } else if (which == 0) {
                    size_t off = (bh * 2048 + nn) * 64 + d;
#pragma unroll
                    for (int r = 0; r < 4; r++)
                        outQ[off + (size_t)r * 64] = f2b(acc[m][n][r] * 0.125f);
                } else {
                    size_t off = (bh * 2048 + nn) * 64 + d;
#pragma unroll
                    for (int r = 0; r < 4; r++)
                        outK[off + (size_t)r * 64] = f2b(acc[m][n][r]);
                }
            } else {
#pragma unroll
                for (int r = 0; r < 4; r++)
                    outF[(size_t)(row + r) * N + col] = acc[m][n][r];
            }
        }
    }
}

// ---------------- flash attention: softcap + causal + gate ----------------
// LDS-shared K/V (L1-BW fix), double-buffered, XOR-swizzled ds_read_b128.
// Poly softcap (LOG2E folded): e2 = x * fma(x2, fma(x2, LC2, LC1), LOG2E).
// DIAGONAL PEELED: off-diagonal iterations carry no causal-mask VALU (the
// mask is provably a no-op there: max k = jt*64+63 < qt*64 <= qglob).
// Staging addresses hoisted to loop-invariant per-lane pointers (+jn*stride).
// 512 blocks = 32 bh x 16 pairs ({p,31-p} = 33 iters, balanced); 4 waves.

__global__ __launch_bounds__(256)
void attn_kernel(const unsigned short* __restrict__ Q,
                 const unsigned short* __restrict__ Kg,
                 const unsigned short* __restrict__ Vp,
                 const float* __restrict__ Gates,
                 unsigned short* __restrict__ Out) {
    __shared__ unsigned short lds[2][2][64][64];   // [dbuf][K|V][row][col] = 32KB

    const int lane = threadIdx.x & 63;
    const int w = threadIdx.x >> 6;
    const int g = lane >> 4;
    const int ql = lane & 15;
    const int sw = ql & 7;
    const int srow = lane >> 3;       // 0..7
    const int sch = lane & 7;

    const int wgid = (blockIdx.x & 7) * 64 + (blockIdx.x >> 3);
    const int bh = wgid >> 4;
    const int pair = wgid & 15;
    const int b = bh >> 4;
    const int h = bh & 15;

    const size_t headBase = (size_t)bh * 2048 * 64;
    const size_t vBase = (size_t)bh * 131072;

    const int koff0 = ((g) ^ sw) * 8;
    const int koff1 = ((g + 4) ^ sw) * 8;
    const int voff0 = ((2 * g) ^ sw) * 8;
    const int voff1 = ((2 * g + 1) ^ sw) * 8;

    // loop-invariant staging source pointers (row = w*16 + {0,8} + srow)
    const int ch = sch ^ srow;        // row&7 == srow for both i
    const unsigned short* kSt0 = Kg + headBase + (size_t)(w * 16 + srow) * 64 + ch * 8;
    const unsigned short* kSt1 = kSt0 + 8 * 64;
    const unsigned short* vSt0 = Vp + vBase + (size_t)(w * 16 + srow) * 2048 + ch * 8;
    const unsigned short* vSt1 = vSt0 + 8 * 2048;

    auto STAGE = [&](int jn, int buf) {
        gload_lds16(kSt0 + (size_t)jn * 4096, (void*)&lds[buf][0][w * 16][0]);
        gload_lds16(kSt1 + (size_t)jn * 4096, (void*)&lds[buf][0][w * 16 + 8][0]);
        gload_lds16(vSt0 + jn * 64, (void*)&lds[buf][1][w * 16][0]);
        gload_lds16(vSt1 + jn * 64, (void*)&lds[buf][1][w * 16 + 8][0]);
    };

    const float LOG2E = 1.4426950408889634f;
    const float LC1 = -1.9235933878519511e-4f;   // LOG2E * -(1/3)/2500
    const float LC2 = 3.0777494205631219e-8f;    // LOG2E * (2/15)/2500^2

    for (int half = 0; half < 2; half++) {
        const int qt = half ? (31 - pair) : pair;
        const int qglob = qt * 64 + w * 16 + ql;

        const unsigned short* qp = Q + headBase + (size_t)qglob * 64 + g * 8;
        bf16x8 qa0 = *(const bf16x8*)qp;
        bf16x8 qa1 = *(const bf16x8*)(qp + 32);

        float lsum = 0.f;
        f32x4 o[4];
#pragma unroll
        for (int n = 0; n < 4; n++) o[n] = (f32x4){0.f, 0.f, 0.f, 0.f};

        auto COMPUTE = [&](int jt, int bb, bool diag) {
            const unsigned short* KL = &lds[bb][0][0][0];
            const unsigned short* VL = &lds[bb][1][0][0];

            f32x4 s4[4];
#pragma unroll
            for (int n = 0; n < 4; n++) {
                const unsigned short* kr = KL + (16 * n + ql) * 64;
                bf16x8 k0 = *(const bf16x8*)(kr + koff0);
                bf16x8 k1 = *(const bf16x8*)(kr + koff1);
                f32x4 sv = (f32x4){0.f, 0.f, 0.f, 0.f};
                sv = __builtin_amdgcn_mfma_f32_16x16x32_bf16(k0, qa0, sv, 0, 0, 0);
                sv = __builtin_amdgcn_mfma_f32_16x16x32_bf16(k1, qa1, sv, 0, 0, 0);
                s4[n] = sv;
            }

            float rs = 0.f;
#pragma unroll
            for (int n = 0; n < 4; n++) {
                int k0c = jt * 64 + n * 16 + 4 * g;
#pragma unroll
                for (int r = 0; r < 4; r++) {
                    float xx = s4[n][r];
                    float x2 = xx * xx;
                    float e2 = xx * __builtin_fmaf(x2, __builtin_fmaf(x2, LC2, LC1), LOG2E);
                    if (diag && (k0c + r > qglob)) e2 = -1e30f;
                    float p = __builtin_amdgcn_exp2f(e2);
                    s4[n][r] = p;
                    rs += p;
                }
            }
            lsum += rs;

            union PU { unsigned int u[4]; bf16x8 v; };
            PU p0, p1;
            p0.u[0] = cvtpk(s4[0][0], s4[0][1]);
            p0.u[1] = cvtpk(s4[0][2], s4[0][3]);
            p0.u[2] = cvtpk(s4[1][0], s4[1][1]);
            p0.u[3] = cvtpk(s4[1][2], s4[1][3]);
            p1.u[0] = cvtpk(s4[2][0], s4[2][1]);
            p1.u[1] = cvtpk(s4[2][2], s4[2][3]);
            p1.u[2] = cvtpk(s4[3][0], s4[3][1]);
            p1.u[3] = cvtpk(s4[3][2], s4[3][3]);

#pragma unroll
            for (int n = 0; n < 4; n++) {
                const unsigned short* vr = VL + (16 * n + ql) * 64;
                bf16x8 vA = *(const bf16x8*)(vr + voff0);
                bf16x8 vB = *(const bf16x8*)(vr + voff1);
                o[n] = __builtin_amdgcn_mfma_f32_16x16x32_bf16(vA, p0.v, o[n], 0, 0, 0);
                o[n] = __builtin_amdgcn_mfma_f32_16x16x32_bf16(vB, p1.v, o[n], 0, 0, 0);
            }
        };

        // prologue: tile 0 -> buffer 0
        STAGE(0, 0);
        __syncthreads();

        // off-diagonal iterations: no causal-mask VALU
        for (int jt = 0; jt < qt; ++jt) {
            const int bb = jt & 1;
            STAGE(jt + 1, bb ^ 1);
            COMPUTE(jt, bb, false);
            __syncthreads();
        }
        // diagonal iteration (masked), no staging
        COMPUTE(qt, qt & 1, true);
        __syncthreads();   // protect lds before next half's prologue restage

        float l = lsum;
        l += __shfl_xor(l, 16);
        l += __shfl_xor(l, 32);
        float gate = Gates[(size_t)bh * 2048 + qglob];
        float inv = gate / l;
        unsigned short* orow = Out + ((size_t)(b * 2048) + qglob) * 1024 + h * 64;
#pragma unroll
        for (int n = 0; n < 4; n++) {
            ushort4 st;
            st.x = f2b(o[n][0] * inv);
            st.y = f2b(o[n][1] * inv);
            st.z = f2b(o[n][2] * inv);
            st.w = f2b(o[n][3] * inv);
            *(ushort4*)(orow + n * 16 + 4 * g) = st;
        }
    }
}

// ---------------- launch ----------------

extern "C" void kernel_launch(void* const* d_in, const int* in_sizes, int n_in,
                              void* d_out, int out_size, void* d_ws, size_t ws_size,
                              hipStream_t stream) {
    const float* x       = (const float*)d_in[0];   // [2][2048][1024]
    const float* w_qkv   = (const float*)d_in[1];   // [1024][3072]
    const float* w_gates = (const float*)d_in[2];   // [1024][16]
    const float* w_out   = (const float*)d_in[3];   // [1024][1024]
    float* out = (float*)d_out;                     // [2][2048][1024]

    char* ws = (char*)d_ws;
    unsigned short* x_bf  = (unsigned short*)(ws);                      // 8 MB
    unsigned short* wqkvT = (unsigned short*)(ws + ((size_t)8  << 20)); // 6 MB
    unsigned short* woutT = (unsigned short*)(ws + ((size_t)14 << 20)); // 2 MB
    unsigned short* qB    = (unsigned short*)(ws + ((size_t)16 << 20)); // 8 MB
    unsigned short* kB    = (unsigned short*)(ws + ((size_t)24 << 20)); // 8 MB
    unsigned short* vP    = (unsigned short*)(ws + ((size_t)32 << 20)); // 8 MB (permuted V)
    float*          gates = (float*)(ws + ((size_t)40 << 20));          // 256 KB
    unsigned short* attnO = (unsigned short*)(ws + ((size_t)41 << 20)); // 8 MB

    cvtgates_kernel<<<dim3(4096), dim3(256), 0, stream>>>(x, w_gates, x_bf, gates);
    transpose_cvt2<<<dim3(128, 32), dim3(32, 8), 0, stream>>>(w_qkv, w_out, wqkvT, woutT);

    gemm_bt_kernel<0><<<dim3(3072 / 128, 4096 / 128), dim3(256), 0, stream>>>(
        x_bf, wqkvT, 4096, 3072, 1024, qB, kB, vP, (float*)nullptr);

    attn_kernel<<<dim3(512), dim3(256), 0, stream>>>(qB, kB, vP, gates, attnO);

    gemm_bt_kernel<1><<<dim3(1024 / 128, 4096 / 128), dim3(256), 0, stream>>>(
        attnO, woutT, 4096, 1024, 1024, nullptr, nullptr, nullptr, out);
}

// Round 16
// 137.909 us; speedup vs baseline: 1.8922x; 1.0550x over previous
//
#include <hip/hip_runtime.h>
#include <hip/hip_bf16.h>

typedef __bf16 bf16x8 __attribute__((ext_vector_type(8)));
typedef float f32x4 __attribute__((ext_vector_type(4)));

__device__ __forceinline__ unsigned short f2b(float f) {
    union { float f; unsigned int u; } v; v.f = f;
    unsigned int r = (v.u + 0x7FFFu + ((v.u >> 16) & 1u)) >> 16;
    return (unsigned short)r;
}

__device__ __forceinline__ unsigned int cvtpk(float lo, float hi) {
    unsigned int r;
    asm("v_cvt_pk_bf16_f32 %0, %1, %2" : "=v"(r) : "v"(lo), "v"(hi));
    return r;
}

__device__ __forceinline__ void gload_lds16(const void* g, void* l) {
    __builtin_amdgcn_global_load_lds((__attribute__((address_space(1))) void*)g,
                                     (__attribute__((address_space(3))) void*)l,
                                     16, 0, 0);
}

// ---- fused convert + gates: x -> x_bf (bf16), gates = sigmoid(x @ wg) ----

__global__ __launch_bounds__(256) void cvtgates_kernel(const float* __restrict__ x,
                                                       const float* __restrict__ wg,
                                                       unsigned short* __restrict__ xb,
                                                       float* __restrict__ gates) {
    __shared__ float xs[1024];
    __shared__ float red[16][17];
    const int row = blockIdx.x;          // b*2048+n
    const int t = threadIdx.x;
    const float* xr = x + (size_t)row * 1024;
    float4 f = *(const float4*)(xr + t * 4);
    *(float4*)(xs + t * 4) = f;
    ushort4 u;
    u.x = f2b(f.x); u.y = f2b(f.y); u.z = f2b(f.z); u.w = f2b(f.w);
    *(ushort4*)(xb + (size_t)row * 1024 + t * 4) = u;
    __syncthreads();
    const int h = t & 15, fi = t >> 4;
    float s = 0.f;
    for (int ff = fi; ff < 1024; ff += 16)
        s += xs[ff] * wg[ff * 16 + h];
    red[fi][h] = s;
    __syncthreads();
    if (t < 16) {
        float tot = 0.f;
#pragma unroll
        for (int i = 0; i < 16; i++) tot += red[i][t];
        int b = row >> 11, n = row & 2047;
        gates[((size_t)(b * 16 + t)) * 2048 + n] = 1.f / (1.f + __expf(-tot));
    }
}

// ---- merged weight transposes: w_qkv (1024x3072) and w_out (1024x1024) ----

__global__ __launch_bounds__(256) void transpose_cvt2(const float* __restrict__ wq,
                                                      const float* __restrict__ wo,
                                                      unsigned short* __restrict__ outq,
                                                      unsigned short* __restrict__ outo) {
    __shared__ float t[32][33];
    const int bx = blockIdx.x;
    const float* in;
    unsigned short* out;
    int C, c0;
    if (bx < 96) { in = wq; out = outq; C = 3072; c0 = bx * 32; }
    else         { in = wo; out = outo; C = 1024; c0 = (bx - 96) * 32; }
    const int r0 = blockIdx.y * 32;      // R = 1024
    const int tx = threadIdx.x, ty = threadIdx.y;
#pragma unroll
    for (int i = 0; i < 4; i++)
        t[ty + i * 8][tx] = in[(size_t)(r0 + ty + i * 8) * C + c0 + tx];
    __syncthreads();
#pragma unroll
    for (int i = 0; i < 4; i++)
        out[(size_t)(c0 + ty + i * 8) * 1024 + r0 + tx] = f2b(t[tx][ty + i * 8]);
}

// ---------------- GEMM: C = A[M][K] * Bt[N][K]^T, bf16 in, fp32 acc ----------------
// BK=32 (measured faster than BK=64). Template WN = wave-split in N:
//   WN=2: 128x128 tile, 4 waves as 2x2 (gemm0)
//   WN=1: 128x64 tile, 4 waves as 4x1 (gemm1: doubles grid to 2 blocks/CU)
// EPI 0: Q (x0.125), K as [b][h][n][d]; V directly in Vp[bh][d][permC(nn)],
//   permC(nn) = (nn&~63) + ((nn>>2)&3)*16 + ((nn>>4)&3)*4 + (nn&3).
// EPI 1: fp32 out [M][N].

template <int EPI, int WN>
__global__ __launch_bounds__(256)
void gemm_bt_kernel(const unsigned short* __restrict__ A,
                    const unsigned short* __restrict__ Bt,
                    int M, int N, int K,
                    unsigned short* __restrict__ outQ,
                    unsigned short* __restrict__ outK,
                    unsigned short* __restrict__ outV,
                    float* __restrict__ outF) {
    constexpr int WM = 4 / WN;           // wave row-groups
    constexpr int MF = 8 / WM;           // m fragments per wave (4 or 2)
    constexpr int BN = 64 * WN;          // tile N (128 or 64)
    __shared__ unsigned short As[128 * 32];
    __shared__ unsigned short Bs[BN * 32];
    const int lane = threadIdx.x & 63;
    const int w = threadIdx.x >> 6;
    const int wr = w / WN, wc = w % WN;
    const int tm = blockIdx.y * 128;
    const int tn = blockIdx.x * BN;

    f32x4 acc[MF][4];
#pragma unroll
    for (int m = 0; m < MF; m++)
#pragma unroll
        for (int n = 0; n < 4; n++) acc[m][n] = (f32x4){0.f, 0.f, 0.f, 0.f};

    const int sRow = lane >> 2;
    const int sCol = (lane & 3) * 8;
    const int fragA = (wr * (16 * MF) + (lane & 15)) * 32 + (lane >> 4) * 8;
    const int fragB = (wc * 64 + (lane & 15)) * 32 + (lane >> 4) * 8;

    for (int k0 = 0; k0 < K; k0 += 32) {
#pragma unroll
        for (int i = 0; i < 2; i++) {
            int chunk = w * 2 + i;
            int r = chunk * 16 + sRow;
            gload_lds16(A + (size_t)(tm + r) * K + k0 + sCol, (void*)(As + chunk * 512));
            if (WN == 2)
                gload_lds16(Bt + (size_t)(tn + r) * K + k0 + sCol, (void*)(Bs + chunk * 512));
        }
        if (WN == 1) {
            int r = w * 16 + sRow;
            gload_lds16(Bt + (size_t)(tn + r) * K + k0 + sCol, (void*)(Bs + w * 512));
        }
        __syncthreads();
        bf16x8 af[MF], bg[4];
#pragma unroll
        for (int m = 0; m < MF; m++) af[m] = *(const bf16x8*)(As + fragA + m * 16 * 32);
#pragma unroll
        for (int n = 0; n < 4; n++) bg[n] = *(const bf16x8*)(Bs + fragB + n * 16 * 32);
#pragma unroll
        for (int m = 0; m < MF; m++)
#pragma unroll
            for (int n = 0; n < 4; n++)
                acc[m][n] = __builtin_amdgcn_mfma_f32_16x16x32_bf16(af[m], bg[n], acc[m][n], 0, 0, 0);
        __syncthreads();
    }

#pragma unroll
    for (int m = 0; m < MF; m++) {
        int row = tm + wr * (16 * MF) + m * 16 + (lane >> 4) * 4;
#pragma unroll
        for (int n = 0; n < 4; n++) {
            int col = tn + wc * 64 + n * 16 + (lane & 15);
            if (EPI == 0) {
                int which = col >> 10;
                int hh = (col >> 6) & 15;
                int d = col & 63;
                int b0 = row >> 11;
                int nn = row & 2047;             // nn % 4 == 0
                size_t bh = (size_t)(b0 * 16 + hh);
                if (which == 2) {
                    int i6 = nn & 63;
                    int pc = (nn & ~63) + ((i6 >> 2) & 3) * 16 + ((i6 >> 4) & 3) * 4;
                    ushort4 st;
                    st.x = f2b(acc[m][n][0]);
                    st.y = f2b(acc[m][n][1]);
                    st.z = f2b(acc[m][n][2]);
                    st.w = f2b(acc[m][n][3]);
                    *(ushort4*)(outV + bh * 131072 + (size_t)d * 2048 + pc) = st;
                } else if (which == 0) {
                    size_t off = (bh * 2048 + nn) * 64 + d;
#pragma unroll
                    for (int r = 0; r < 4; r++)
                        outQ[off + (size_t)r * 64] = f2b(acc[m][n][r] * 0.125f);
                } else {
                    size_t off = (bh * 2048 + nn) * 64 + d;
#pragma unroll
                    for (int r = 0; r < 4; r++)
                        outK[off + (size_t)r * 64] = f2b(acc[m][n][r]);
                }
            } else {
#pragma unroll
                for (int r = 0; r < 4; r++)
                    outF[(size_t)(row + r) * N + col] = acc[m][n][r];
            }
        }
    }
}

// ---------------- flash attention: softcap + causal + gate ----------------
// LDS-shared K/V (L1-BW fix), double-buffered, XOR-swizzled ds_read_b128.
// Poly softcap (LOG2E folded); diagonal peeled (off-diag iters carry no
// causal-mask VALU); loop-invariant staging pointers.
// 512 blocks = 32 bh x 16 pairs ({p,31-p} = 33 iters, balanced); 4 waves.

__global__ __launch_bounds__(256)
void attn_kernel(const unsigned short* __restrict__ Q,
                 const unsigned short* __restrict__ Kg,
                 const unsigned short* __restrict__ Vp,
                 const float* __restrict__ Gates,
                 unsigned short* __restrict__ Out) {
    __shared__ unsigned short lds[2][2][64][64];   // [dbuf][K|V][row][col] = 32KB

    const int lane = threadIdx.x & 63;
    const int w = threadIdx.x >> 6;
    const int g = lane >> 4;
    const int ql = lane & 15;
    const int sw = ql & 7;
    const int srow = lane >> 3;       // 0..7
    const int sch = lane & 7;

    const int wgid = (blockIdx.x & 7) * 64 + (blockIdx.x >> 3);
    const int bh = wgid >> 4;
    const int pair = wgid & 15;
    const int b = bh >> 4;
    const int h = bh & 15;

    const size_t headBase = (size_t)bh * 2048 * 64;
    const size_t vBase = (size_t)bh * 131072;

    const int koff0 = ((g) ^ sw) * 8;
    const int koff1 = ((g + 4) ^ sw) * 8;
    const int voff0 = ((2 * g) ^ sw) * 8;
    const int voff1 = ((2 * g + 1) ^ sw) * 8;

    const int ch = sch ^ srow;
    const unsigned short* kSt0 = Kg + headBase + (size_t)(w * 16 + srow) * 64 + ch * 8;
    const unsigned short* kSt1 = kSt0 + 8 * 64;
    const unsigned short* vSt0 = Vp + vBase + (size_t)(w * 16 + srow) * 2048 + ch * 8;
    const unsigned short* vSt1 = vSt0 + 8 * 2048;

    auto STAGE = [&](int jn, int buf) {
        gload_lds16(kSt0 + (size_t)jn * 4096, (void*)&lds[buf][0][w * 16][0]);
        gload_lds16(kSt1 + (size_t)jn * 4096, (void*)&lds[buf][0][w * 16 + 8][0]);
        gload_lds16(vSt0 + jn * 64, (void*)&lds[buf][1][w * 16][0]);
        gload_lds16(vSt1 + jn * 64, (void*)&lds[buf][1][w * 16 + 8][0]);
    };

    const float LOG2E = 1.4426950408889634f;
    const float LC1 = -1.9235933878519511e-4f;   // LOG2E * -(1/3)/2500
    const float LC2 = 3.0777494205631219e-8f;    // LOG2E * (2/15)/2500^2

    for (int half = 0; half < 2; half++) {
        const int qt = half ? (31 - pair) : pair;
        const int qglob = qt * 64 + w * 16 + ql;

        const unsigned short* qp = Q + headBase + (size_t)qglob * 64 + g * 8;
        bf16x8 qa0 = *(const bf16x8*)qp;
        bf16x8 qa1 = *(const bf16x8*)(qp + 32);

        float lsum = 0.f;
        f32x4 o[4];
#pragma unroll
        for (int n = 0; n < 4; n++) o[n] = (f32x4){0.f, 0.f, 0.f, 0.f};

        auto COMPUTE = [&](int jt, int bb, bool diag) {
            const unsigned short* KL = &lds[bb][0][0][0];
            const unsigned short* VL = &lds[bb][1][0][0];

            f32x4 s4[4];
#pragma unroll
            for (int n = 0; n < 4; n++) {
                const unsigned short* kr = KL + (16 * n + ql) * 64;
                bf16x8 k0 = *(const bf16x8*)(kr + koff0);
                bf16x8 k1 = *(const bf16x8*)(kr + koff1);
                f32x4 sv = (f32x4){0.f, 0.f, 0.f, 0.f};
                sv = __builtin_amdgcn_mfma_f32_16x16x32_bf16(k0, qa0, sv, 0, 0, 0);
                sv = __builtin_amdgcn_mfma_f32_16x16x32_bf16(k1, qa1, sv, 0, 0, 0);
                s4[n] = sv;
            }

            float rs = 0.f;
#pragma unroll
            for (int n = 0; n < 4; n++) {
                int k0c = jt * 64 + n * 16 + 4 * g;
#pragma unroll
                for (int r = 0; r < 4; r++) {
                    float xx = s4[n][r];
                    float x2 = xx * xx;
                    float e2 = xx * __builtin_fmaf(x2, __builtin_fmaf(x2, LC2, LC1), LOG2E);
                    if (diag && (k0c + r > qglob)) e2 = -1e30f;
                    float p = __builtin_amdgcn_exp2f(e2);
                    s4[n][r] = p;
                    rs += p;
                }
            }
            lsum += rs;

            union PU { unsigned int u[4]; bf16x8 v; };
            PU p0, p1;
            p0.u[0] = cvtpk(s4[0][0], s4[0][1]);
            p0.u[1] = cvtpk(s4[0][2], s4[0][3]);
            p0.u[2] = cvtpk(s4[1][0], s4[1][1]);
            p0.u[3] = cvtpk(s4[1][2], s4[1][3]);
            p1.u[0] = cvtpk(s4[2][0], s4[2][1]);
            p1.u[1] = cvtpk(s4[2][2], s4[2][3]);
            p1.u[2] = cvtpk(s4[3][0], s4[3][1]);
            p1.u[3] = cvtpk(s4[3][2], s4[3][3]);

#pragma unroll
            for (int n = 0; n < 4; n++) {
                const unsigned short* vr = VL + (16 * n + ql) * 64;
                bf16x8 vA = *(const bf16x8*)(vr + voff0);
                bf16x8 vB = *(const bf16x8*)(vr + voff1);
                o[n] = __builtin_amdgcn_mfma_f32_16x16x32_bf16(vA, p0.v, o[n], 0, 0, 0);
                o[n] = __builtin_amdgcn_mfma_f32_16x16x32_bf16(vB, p1.v, o[n], 0, 0, 0);
            }
        };

        STAGE(0, 0);
        __syncthreads();

        for (int jt = 0; jt < qt; ++jt) {
            const int bb = jt & 1;
            STAGE(jt + 1, bb ^ 1);
            COMPUTE(jt, bb, false);
            __syncthreads();
        }
        COMPUTE(qt, qt & 1, true);
        __syncthreads();

        float l = lsum;
        l += __shfl_xor(l, 16);
        l += __shfl_xor(l, 32);
        float gate = Gates[(size_t)bh * 2048 + qglob];
        float inv = gate / l;
        unsigned short* orow = Out + ((size_t)(b * 2048) + qglob) * 1024 + h * 64;
#pragma unroll
        for (int n = 0; n < 4; n++) {
            ushort4 st;
            st.x = f2b(o[n][0] * inv);
            st.y = f2b(o[n][1] * inv);
            st.z = f2b(o[n][2] * inv);
            st.w = f2b(o[n][3] * inv);
            *(ushort4*)(orow + n * 16 + 4 * g) = st;
        }
    }
}

// ---------------- launch ----------------

extern "C" void kernel_launch(void* const* d_in, const int* in_sizes, int n_in,
                              void* d_out, int out_size, void* d_ws, size_t ws_size,
                              hipStream_t stream) {
    const float* x       = (const float*)d_in[0];   // [2][2048][1024]
    const float* w_qkv   = (const float*)d_in[1];   // [1024][3072]
    const float* w_gates = (const float*)d_in[2];   // [1024][16]
    const float* w_out   = (const float*)d_in[3];   // [1024][1024]
    float* out = (float*)d_out;                     // [2][2048][1024]

    char* ws = (char*)d_ws;
    unsigned short* x_bf  = (unsigned short*)(ws);                      // 8 MB
    unsigned short* wqkvT = (unsigned short*)(ws + ((size_t)8  << 20)); // 6 MB
    unsigned short* woutT = (unsigned short*)(ws + ((size_t)14 << 20)); // 2 MB
    unsigned short* qB    = (unsigned short*)(ws + ((size_t)16 << 20)); // 8 MB
    unsigned short* kB    = (unsigned short*)(ws + ((size_t)24 << 20)); // 8 MB
    unsigned short* vP    = (unsigned short*)(ws + ((size_t)32 << 20)); // 8 MB (permuted V)
    float*          gates = (float*)(ws + ((size_t)40 << 20));          // 256 KB
    unsigned short* attnO = (unsigned short*)(ws + ((size_t)41 << 20)); // 8 MB

    cvtgates_kernel<<<dim3(4096), dim3(256), 0, stream>>>(x, w_gates, x_bf, gates);
    transpose_cvt2<<<dim3(128, 32), dim3(32, 8), 0, stream>>>(w_qkv, w_out, wqkvT, woutT);

    gemm_bt_kernel<0, 2><<<dim3(3072 / 128, 4096 / 128), dim3(256), 0, stream>>>(
        x_bf, wqkvT, 4096, 3072, 1024, qB, kB, vP, (float*)nullptr);

    attn_kernel<<<dim3(512), dim3(256), 0, stream>>>(qB, kB, vP, gates, attnO);

    gemm_bt_kernel<1, 1><<<dim3(1024 / 64, 4096 / 128), dim3(256), 0, stream>>>(
        attnO, woutT, 4096, 1024, 1024, nullptr, nullptr, nullptr, out);
}

// Round 17
// 134.009 us; speedup vs baseline: 1.9472x; 1.0291x over previous
//
#include <hip/hip_runtime.h>
#include <hip/hip_bf16.h>

typedef __bf16 bf16x8 __attribute__((ext_vector_type(8)));
typedef float f32x4 __attribute__((ext_vector_type(4)));

__device__ __forceinline__ unsigned short f2b(float f) {
    union { float f; unsigned int u; } v; v.f = f;
    unsigned int r = (v.u + 0x7FFFu + ((v.u >> 16) & 1u)) >> 16;
    return (unsigned short)r;
}

__device__ __forceinline__ unsigned int cvtpk(float lo, float hi) {
    unsigned int r;
    asm("v_cvt_pk_bf16_f32 %0, %1, %2" : "=v"(r) : "v"(lo), "v"(hi));
    return r;
}

__device__ __forceinline__ void gload_lds16(const void* g, void* l) {
    __builtin_amdgcn_global_load_lds((__attribute__((address_space(1))) void*)g,
                                     (__attribute__((address_space(3))) void*)l,
                                     16, 0, 0);
}

// ---- merged pre-pass: cvt x->bf16 + gates (blocks 0..4095), weight
// transposes for w_qkv and w_out (blocks 4096..8191) ----

__global__ __launch_bounds__(256)
void prepass_kernel(const float* __restrict__ x, const float* __restrict__ wg,
                    const float* __restrict__ wq, const float* __restrict__ wo,
                    unsigned short* __restrict__ xb, float* __restrict__ gates,
                    unsigned short* __restrict__ outq, unsigned short* __restrict__ outo) {
    __shared__ float xs[1024];
    __shared__ float red[16][17];
    __shared__ float tt[32][33];
    const int t = threadIdx.x;
    if (blockIdx.x < 4096) {
        const int row = blockIdx.x;          // b*2048+n
        const float* xr = x + (size_t)row * 1024;
        float4 f = *(const float4*)(xr + t * 4);
        *(float4*)(xs + t * 4) = f;
        ushort4 u;
        u.x = f2b(f.x); u.y = f2b(f.y); u.z = f2b(f.z); u.w = f2b(f.w);
        *(ushort4*)(xb + (size_t)row * 1024 + t * 4) = u;
        __syncthreads();
        const int h = t & 15, fi = t >> 4;
        float s = 0.f;
        for (int ff = fi; ff < 1024; ff += 16)
            s += xs[ff] * wg[ff * 16 + h];
        red[fi][h] = s;
        __syncthreads();
        if (t < 16) {
            float tot = 0.f;
#pragma unroll
            for (int i = 0; i < 16; i++) tot += red[i][t];
            int b = row >> 11, n = row & 2047;
            gates[((size_t)(b * 16 + t)) * 2048 + n] = 1.f / (1.f + __expf(-tot));
        }
    } else {
        const int bx = blockIdx.x - 4096;    // 0..4095
        const int colTile = bx & 127;        // 0..127
        const int r0 = (bx >> 7) * 32;       // row tile (R=1024)
        const float* in;
        unsigned short* out;
        int C, c0;
        if (colTile < 96) { in = wq; out = outq; C = 3072; c0 = colTile * 32; }
        else              { in = wo; out = outo; C = 1024; c0 = (colTile - 96) * 32; }
        const int tx = t & 31, ty = t >> 5;
#pragma unroll
        for (int i = 0; i < 4; i++)
            tt[ty + i * 8][tx] = in[(size_t)(r0 + ty + i * 8) * C + c0 + tx];
        __syncthreads();
#pragma unroll
        for (int i = 0; i < 4; i++)
            out[(size_t)(c0 + ty + i * 8) * 1024 + r0 + tx] = f2b(tt[tx][ty + i * 8]);
    }
}

// ---------------- GEMM: C = A[M][K] * Bt[N][K]^T, bf16 in, fp32 acc ----------------
// BK=32. Template WN = wave-split in N: WN=2: 128x128 (gemm0); WN=1: 128x64 (gemm1).
// EPI 0: Q (x0.125), K as [b][h][n][d]; V directly in Vp[bh][d][permC(nn)],
//   permC(nn) = (nn&~63) + ((nn>>2)&3)*16 + ((nn>>4)&3)*4 + (nn&3).
// EPI 1: fp32 out [M][N].

template <int EPI, int WN>
__global__ __launch_bounds__(256)
void gemm_bt_kernel(const unsigned short* __restrict__ A,
                    const unsigned short* __restrict__ Bt,
                    int M, int N, int K,
                    unsigned short* __restrict__ outQ,
                    unsigned short* __restrict__ outK,
                    unsigned short* __restrict__ outV,
                    float* __restrict__ outF) {
    constexpr int WM = 4 / WN;
    constexpr int MF = 8 / WM;
    constexpr int BN = 64 * WN;
    __shared__ unsigned short As[128 * 32];
    __shared__ unsigned short Bs[BN * 32];
    const int lane = threadIdx.x & 63;
    const int w = threadIdx.x >> 6;
    const int wr = w / WN, wc = w % WN;
    const int tm = blockIdx.y * 128;
    const int tn = blockIdx.x * BN;

    f32x4 acc[MF][4];
#pragma unroll
    for (int m = 0; m < MF; m++)
#pragma unroll
        for (int n = 0; n < 4; n++) acc[m][n] = (f32x4){0.f, 0.f, 0.f, 0.f};

    const int sRow = lane >> 2;
    const int sCol = (lane & 3) * 8;
    const int fragA = (wr * (16 * MF) + (lane & 15)) * 32 + (lane >> 4) * 8;
    const int fragB = (wc * 64 + (lane & 15)) * 32 + (lane >> 4) * 8;

    for (int k0 = 0; k0 < K; k0 += 32) {
#pragma unroll
        for (int i = 0; i < 2; i++) {
            int chunk = w * 2 + i;
            int r = chunk * 16 + sRow;
            gload_lds16(A + (size_t)(tm + r) * K + k0 + sCol, (void*)(As + chunk * 512));
            if (WN == 2)
                gload_lds16(Bt + (size_t)(tn + r) * K + k0 + sCol, (void*)(Bs + chunk * 512));
        }
        if (WN == 1) {
            int r = w * 16 + sRow;
            gload_lds16(Bt + (size_t)(tn + r) * K + k0 + sCol, (void*)(Bs + w * 512));
        }
        __syncthreads();
        bf16x8 af[MF], bg[4];
#pragma unroll
        for (int m = 0; m < MF; m++) af[m] = *(const bf16x8*)(As + fragA + m * 16 * 32);
#pragma unroll
        for (int n = 0; n < 4; n++) bg[n] = *(const bf16x8*)(Bs + fragB + n * 16 * 32);
#pragma unroll
        for (int m = 0; m < MF; m++)
#pragma unroll
            for (int n = 0; n < 4; n++)
                acc[m][n] = __builtin_amdgcn_mfma_f32_16x16x32_bf16(af[m], bg[n], acc[m][n], 0, 0, 0);
        __syncthreads();
    }

#pragma unroll
    for (int m = 0; m < MF; m++) {
        int row = tm + wr * (16 * MF) + m * 16 + (lane >> 4) * 4;
#pragma unroll
        for (int n = 0; n < 4; n++) {
            int col = tn + wc * 64 + n * 16 + (lane & 15);
            if (EPI == 0) {
                int which = col >> 10;
                int hh = (col >> 6) & 15;
                int d = col & 63;
                int b0 = row >> 11;
                int nn = row & 2047;             // nn % 4 == 0
                size_t bh = (size_t)(b0 * 16 + hh);
                if (which == 2) {
                    int i6 = nn & 63;
                    int pc = (nn & ~63) + ((i6 >> 2) & 3) * 16 + ((i6 >> 4) & 3) * 4;
                    ushort4 st;
                    st.x = f2b(acc[m][n][0]);
                    st.y = f2b(acc[m][n][1]);
                    st.z = f2b(acc[m][n][2]);
                    st.w = f2b(acc[m][n][3]);
                    *(ushort4*)(outV + bh * 131072 + (size_t)d * 2048 + pc) = st;
                } else if (which == 0) {
                    size_t off = (bh * 2048 + nn) * 64 + d;
#pragma unroll
                    for (int r = 0; r < 4; r++)
                        outQ[off + (size_t)r * 64] = f2b(acc[m][n][r] * 0.125f);
                } else {
                    size_t off = (bh * 2048 + nn) * 64 + d;
#pragma unroll
                    for (int r = 0; r < 4; r++)
                        outK[off + (size_t)r * 64] = f2b(acc[m][n][r]);
                }
            } else {
#pragma unroll
                for (int r = 0; r < 4; r++)
                    outF[(size_t)(row + r) * N + col] = acc[m][n][r];
            }
        }
    }
}

// ---------------- flash attention: softcap + causal + gate ----------------
// LDS-shared K/V; PAIRED 64-tiles: two tiles staged per barrier interval
// (64KB LDS, 2 slots x double-buffer) -> barrier count halved (34 -> ~18),
// prefetch distance doubled. Verified 64-col COMPUTE/STAGE unchanged.
// Poly softcap (LOG2E folded); diagonal confined to the final pair (runtime
// mask only there); s_setprio(1) around MFMA clusters (T5, attn-positive).
// 512 blocks = 32 bh x 16 pairs ({p,31-p}, balanced); 4 waves x 16 q-rows.

__global__ __launch_bounds__(256)
void attn_kernel(const unsigned short* __restrict__ Q,
                 const unsigned short* __restrict__ Kg,
                 const unsigned short* __restrict__ Vp,
                 const float* __restrict__ Gates,
                 unsigned short* __restrict__ Out) {
    __shared__ unsigned short lds[2][2][2][64][64];  // [dbuf][slot][K|V][row][col] = 64KB

    const int lane = threadIdx.x & 63;
    const int w = threadIdx.x >> 6;
    const int g = lane >> 4;
    const int ql = lane & 15;
    const int sw = ql & 7;
    const int srow = lane >> 3;
    const int sch = lane & 7;

    const int wgid = (blockIdx.x & 7) * 64 + (blockIdx.x >> 3);
    const int bh = wgid >> 4;
    const int pair = wgid & 15;
    const int b = bh >> 4;
    const int h = bh & 15;

    const size_t headBase = (size_t)bh * 2048 * 64;
    const size_t vBase = (size_t)bh * 131072;

    const int koff0 = ((g) ^ sw) * 8;
    const int koff1 = ((g + 4) ^ sw) * 8;
    const int voff0 = ((2 * g) ^ sw) * 8;
    const int voff1 = ((2 * g + 1) ^ sw) * 8;

    const int ch = sch ^ srow;
    const unsigned short* kSt0 = Kg + headBase + (size_t)(w * 16 + srow) * 64 + ch * 8;
    const unsigned short* kSt1 = kSt0 + 8 * 64;
    const unsigned short* vSt0 = Vp + vBase + (size_t)(w * 16 + srow) * 2048 + ch * 8;
    const unsigned short* vSt1 = vSt0 + 8 * 2048;

    auto STAGE = [&](int jn, int buf, int slot) {
        gload_lds16(kSt0 + (size_t)jn * 4096, (void*)&lds[buf][slot][0][w * 16][0]);
        gload_lds16(kSt1 + (size_t)jn * 4096, (void*)&lds[buf][slot][0][w * 16 + 8][0]);
        gload_lds16(vSt0 + jn * 64, (void*)&lds[buf][slot][1][w * 16][0]);
        gload_lds16(vSt1 + jn * 64, (void*)&lds[buf][slot][1][w * 16 + 8][0]);
    };

    const float LOG2E = 1.4426950408889634f;
    const float LC1 = -1.9235933878519511e-4f;   // LOG2E * -(1/3)/2500
    const float LC2 = 3.0777494205631219e-8f;    // LOG2E * (2/15)/2500^2

    for (int half = 0; half < 2; half++) {
        const int qt = half ? (31 - pair) : pair;
        const int qglob = qt * 64 + w * 16 + ql;
        const int T = qt + 1;
        const int nPairs = (T + 1) >> 1;

        const unsigned short* qp = Q + headBase + (size_t)qglob * 64 + g * 8;
        bf16x8 qa0 = *(const bf16x8*)qp;
        bf16x8 qa1 = *(const bf16x8*)(qp + 32);

        float lsum = 0.f;
        f32x4 o[4];
#pragma unroll
        for (int n = 0; n < 4; n++) o[n] = (f32x4){0.f, 0.f, 0.f, 0.f};

        auto COMPUTE = [&](int jt, int bb, int slot, bool diag) {
            const unsigned short* KL = &lds[bb][slot][0][0][0];
            const unsigned short* VL = &lds[bb][slot][1][0][0];

            f32x4 s4[4];
            __builtin_amdgcn_s_setprio(1);
#pragma unroll
            for (int n = 0; n < 4; n++) {
                const unsigned short* kr = KL + (16 * n + ql) * 64;
                bf16x8 k0 = *(const bf16x8*)(kr + koff0);
                bf16x8 k1 = *(const bf16x8*)(kr + koff1);
                f32x4 sv = (f32x4){0.f, 0.f, 0.f, 0.f};
                sv = __builtin_amdgcn_mfma_f32_16x16x32_bf16(k0, qa0, sv, 0, 0, 0);
                sv = __builtin_amdgcn_mfma_f32_16x16x32_bf16(k1, qa1, sv, 0, 0, 0);
                s4[n] = sv;
            }
            __builtin_amdgcn_s_setprio(0);

            float rs = 0.f;
#pragma unroll
            for (int n = 0; n < 4; n++) {
                int k0c = jt * 64 + n * 16 + 4 * g;
#pragma unroll
                for (int r = 0; r < 4; r++) {
                    float xx = s4[n][r];
                    float x2 = xx * xx;
                    float e2 = xx * __builtin_fmaf(x2, __builtin_fmaf(x2, LC2, LC1), LOG2E);
                    if (diag && (k0c + r > qglob)) e2 = -1e30f;
                    float p = __builtin_amdgcn_exp2f(e2);
                    s4[n][r] = p;
                    rs += p;
                }
            }
            lsum += rs;

            union PU { unsigned int u[4]; bf16x8 v; };
            PU p0, p1;
            p0.u[0] = cvtpk(s4[0][0], s4[0][1]);
            p0.u[1] = cvtpk(s4[0][2], s4[0][3]);
            p0.u[2] = cvtpk(s4[1][0], s4[1][1]);
            p0.u[3] = cvtpk(s4[1][2], s4[1][3]);
            p1.u[0] = cvtpk(s4[2][0], s4[2][1]);
            p1.u[1] = cvtpk(s4[2][2], s4[2][3]);
            p1.u[2] = cvtpk(s4[3][0], s4[3][1]);
            p1.u[3] = cvtpk(s4[3][2], s4[3][3]);

            __builtin_amdgcn_s_setprio(1);
#pragma unroll
            for (int n = 0; n < 4; n++) {
                const unsigned short* vr = VL + (16 * n + ql) * 64;
                bf16x8 vA = *(const bf16x8*)(vr + voff0);
                bf16x8 vB = *(const bf16x8*)(vr + voff1);
                o[n] = __builtin_amdgcn_mfma_f32_16x16x32_bf16(vA, p0.v, o[n], 0, 0, 0);
                o[n] = __builtin_amdgcn_mfma_f32_16x16x32_bf16(vB, p1.v, o[n], 0, 0, 0);
            }
            __builtin_amdgcn_s_setprio(0);
        };

        // prologue: stage pair 0 (tiles 0, 1 if present) into buffer 0
        STAGE(0, 0, 0);
        if (1 <= qt) STAGE(1, 0, 1);
        __syncthreads();

        // full off-diagonal pairs
        for (int p = 0; p < nPairs - 1; ++p) {
            const int bb = p & 1;
            const int j2 = 2 * (p + 1);
            STAGE(j2, bb ^ 1, 0);
            if (j2 + 1 <= qt) STAGE(j2 + 1, bb ^ 1, 1);
            COMPUTE(2 * p, bb, 0, false);
            COMPUTE(2 * p + 1, bb, 1, false);
            __syncthreads();
        }
        // final pair (contains the diagonal)
        {
            const int p = nPairs - 1;
            const int bb = p & 1;
            COMPUTE(2 * p, bb, 0, 2 * p == qt);
            if (2 * p + 1 <= qt) COMPUTE(2 * p + 1, bb, 1, true);
            __syncthreads();
        }

        float l = lsum;
        l += __shfl_xor(l, 16);
        l += __shfl_xor(l, 32);
        float gate = Gates[(size_t)bh * 2048 + qglob];
        float inv = gate / l;
        unsigned short* orow = Out + ((size_t)(b * 2048) + qglob) * 1024 + h * 64;
#pragma unroll
        for (int n = 0; n < 4; n++) {
            ushort4 st;
            st.x = f2b(o[n][0] * inv);
            st.y = f2b(o[n][1] * inv);
            st.z = f2b(o[n][2] * inv);
            st.w = f2b(o[n][3] * inv);
            *(ushort4*)(orow + n * 16 + 4 * g) = st;
        }
    }
}

// ---------------- launch ----------------

extern "C" void kernel_launch(void* const* d_in, const int* in_sizes, int n_in,
                              void* d_out, int out_size, void* d_ws, size_t ws_size,
                              hipStream_t stream) {
    const float* x       = (const float*)d_in[0];   // [2][2048][1024]
    const float* w_qkv   = (const float*)d_in[1];   // [1024][3072]
    const float* w_gates = (const float*)d_in[2];   // [1024][16]
    const float* w_out   = (const float*)d_in[3];   // [1024][1024]
    float* out = (float*)d_out;                     // [2][2048][1024]

    char* ws = (char*)d_ws;
    unsigned short* x_bf  = (unsigned short*)(ws);                      // 8 MB
    unsigned short* wqkvT = (unsigned short*)(ws + ((size_t)8  << 20)); // 6 MB
    unsigned short* woutT = (unsigned short*)(ws + ((size_t)14 << 20)); // 2 MB
    unsigned short* qB    = (unsigned short*)(ws + ((size_t)16 << 20)); // 8 MB
    unsigned short* kB    = (unsigned short*)(ws + ((size_t)24 << 20)); // 8 MB
    unsigned short* vP    = (unsigned short*)(ws + ((size_t)32 << 20)); // 8 MB (permuted V)
    float*          gates = (float*)(ws + ((size_t)40 << 20));          // 256 KB
    unsigned short* attnO = (unsigned short*)(ws + ((size_t)41 << 20)); // 8 MB

    prepass_kernel<<<dim3(8192), dim3(256), 0, stream>>>(
        x, w_gates, w_qkv, w_out, x_bf, gates, wqkvT, woutT);

    gemm_bt_kernel<0, 2><<<dim3(3072 / 128, 4096 / 128), dim3(256), 0, stream>>>(
        x_bf, wqkvT, 4096, 3072, 1024, qB, kB, vP, (float*)nullptr);

    attn_kernel<<<dim3(512), dim3(256), 0, stream>>>(qB, kB, vP, gates, attnO);

    gemm_bt_kernel<1, 1><<<dim3(1024 / 64, 4096 / 128), dim3(256), 0, stream>>>(
        attnO, woutT, 4096, 1024, 1024, nullptr, nullptr, nullptr, out);
}

// Round 18
// 127.085 us; speedup vs baseline: 2.0533x; 1.0545x over previous
//
#include <hip/hip_runtime.h>
#include <hip/hip_bf16.h>

typedef __bf16 bf16x8 __attribute__((ext_vector_type(8)));
typedef float f32x4 __attribute__((ext_vector_type(4)));

__device__ __forceinline__ unsigned short f2b(float f) {
    union { float f; unsigned int u; } v; v.f = f;
    unsigned int r = (v.u + 0x7FFFu + ((v.u >> 16) & 1u)) >> 16;
    return (unsigned short)r;
}

__device__ __forceinline__ unsigned int cvtpk(float lo, float hi) {
    unsigned int r;
    asm("v_cvt_pk_bf16_f32 %0, %1, %2" : "=v"(r) : "v"(lo), "v"(hi));
    return r;
}

__device__ __forceinline__ void gload_lds16(const void* g, void* l) {
    __builtin_amdgcn_global_load_lds((__attribute__((address_space(1))) void*)g,
                                     (__attribute__((address_space(3))) void*)l,
                                     16, 0, 0);
}

// ---- merged pre-pass: cvt x->bf16 + gates (blocks 0..4095), weight
// transposes for w_qkv and w_out (blocks 4096..8191) ----

__global__ __launch_bounds__(256)
void prepass_kernel(const float* __restrict__ x, const float* __restrict__ wg,
                    const float* __restrict__ wq, const float* __restrict__ wo,
                    unsigned short* __restrict__ xb, float* __restrict__ gates,
                    unsigned short* __restrict__ outq, unsigned short* __restrict__ outo) {
    __shared__ float xs[1024];
    __shared__ float red[16][17];
    __shared__ float tt[32][33];
    const int t = threadIdx.x;
    if (blockIdx.x < 4096) {
        const int row = blockIdx.x;          // b*2048+n
        const float* xr = x + (size_t)row * 1024;
        float4 f = *(const float4*)(xr + t * 4);
        *(float4*)(xs + t * 4) = f;
        ushort4 u;
        u.x = f2b(f.x); u.y = f2b(f.y); u.z = f2b(f.z); u.w = f2b(f.w);
        *(ushort4*)(xb + (size_t)row * 1024 + t * 4) = u;
        __syncthreads();
        const int h = t & 15, fi = t >> 4;
        float s = 0.f;
        for (int ff = fi; ff < 1024; ff += 16)
            s += xs[ff] * wg[ff * 16 + h];
        red[fi][h] = s;
        __syncthreads();
        if (t < 16) {
            float tot = 0.f;
#pragma unroll
            for (int i = 0; i < 16; i++) tot += red[i][t];
            int b = row >> 11, n = row & 2047;
            gates[((size_t)(b * 16 + t)) * 2048 + n] = 1.f / (1.f + __expf(-tot));
        }
    } else {
        const int bx = blockIdx.x - 4096;    // 0..4095
        const int colTile = bx & 127;        // 0..127
        const int r0 = (bx >> 7) * 32;       // row tile (R=1024)
        const float* in;
        unsigned short* out;
        int C, c0;
        if (colTile < 96) { in = wq; out = outq; C = 3072; c0 = colTile * 32; }
        else              { in = wo; out = outo; C = 1024; c0 = (colTile - 96) * 32; }
        const int tx = t & 31, ty = t >> 5;
#pragma unroll
        for (int i = 0; i < 4; i++)
            tt[ty + i * 8][tx] = in[(size_t)(r0 + ty + i * 8) * C + c0 + tx];
        __syncthreads();
#pragma unroll
        for (int i = 0; i < 4; i++)
            out[(size_t)(c0 + ty + i * 8) * 1024 + r0 + tx] = f2b(tt[tx][ty + i * 8]);
    }
}

// ---------------- GEMM: C = A[M][K] * Bt[N][K]^T, bf16 in, fp32 acc ----------------
// BK=32, DOUBLE-BUFFERED staging: STAGE(k0+32 -> buf^1) issued before the
// MFMAs on buf, one barrier per iter (stage latency hides under compute;
// barrier count halved). Template WN: 2 = 128x128 (gemm0); 1 = 128x64 (gemm1).
// EPI 0: Q (x0.125), K as [b][h][n][d]; V directly in Vp[bh][d][permC(nn)],
//   permC(nn) = (nn&~63) + ((nn>>2)&3)*16 + ((nn>>4)&3)*4 + (nn&3).
// EPI 1: fp32 out [M][N].

template <int EPI, int WN>
__global__ __launch_bounds__(256)
void gemm_bt_kernel(const unsigned short* __restrict__ A,
                    const unsigned short* __restrict__ Bt,
                    int M, int N, int K,
                    unsigned short* __restrict__ outQ,
                    unsigned short* __restrict__ outK,
                    unsigned short* __restrict__ outV,
                    float* __restrict__ outF) {
    constexpr int WM = 4 / WN;
    constexpr int MF = 8 / WM;
    constexpr int BN = 64 * WN;
    __shared__ unsigned short As[2][128 * 32];
    __shared__ unsigned short Bs[2][BN * 32];
    const int lane = threadIdx.x & 63;
    const int w = threadIdx.x >> 6;
    const int wr = w / WN, wc = w % WN;
    const int tm = blockIdx.y * 128;
    const int tn = blockIdx.x * BN;

    f32x4 acc[MF][4];
#pragma unroll
    for (int m = 0; m < MF; m++)
#pragma unroll
        for (int n = 0; n < 4; n++) acc[m][n] = (f32x4){0.f, 0.f, 0.f, 0.f};

    const int sRow = lane >> 2;
    const int sCol = (lane & 3) * 8;
    const int fragA = (wr * (16 * MF) + (lane & 15)) * 32 + (lane >> 4) * 8;
    const int fragB = (wc * 64 + (lane & 15)) * 32 + (lane >> 4) * 8;

    auto STAGE = [&](int k0, int buf) {
#pragma unroll
        for (int i = 0; i < 2; i++) {
            int chunk = w * 2 + i;
            int r = chunk * 16 + sRow;
            gload_lds16(A + (size_t)(tm + r) * K + k0 + sCol, (void*)(As[buf] + chunk * 512));
            if (WN == 2)
                gload_lds16(Bt + (size_t)(tn + r) * K + k0 + sCol, (void*)(Bs[buf] + chunk * 512));
        }
        if (WN == 1) {
            int r = w * 16 + sRow;
            gload_lds16(Bt + (size_t)(tn + r) * K + k0 + sCol, (void*)(Bs[buf] + w * 512));
        }
    };

    STAGE(0, 0);
    __syncthreads();
    int cur = 0;
    for (int k0 = 0; k0 < K; k0 += 32) {
        if (k0 + 32 < K) STAGE(k0 + 32, cur ^ 1);
        bf16x8 af[MF], bg[4];
#pragma unroll
        for (int m = 0; m < MF; m++) af[m] = *(const bf16x8*)(As[cur] + fragA + m * 16 * 32);
#pragma unroll
        for (int n = 0; n < 4; n++) bg[n] = *(const bf16x8*)(Bs[cur] + fragB + n * 16 * 32);
#pragma unroll
        for (int m = 0; m < MF; m++)
#pragma unroll
            for (int n = 0; n < 4; n++)
                acc[m][n] = __builtin_amdgcn_mfma_f32_16x16x32_bf16(af[m], bg[n], acc[m][n], 0, 0, 0);
        __syncthreads();
        cur ^= 1;
    }

#pragma unroll
    for (int m = 0; m < MF; m++) {
        int row = tm + wr * (16 * MF) + m * 16 + (lane >> 4) * 4;
#pragma unroll
        for (int n = 0; n < 4; n++) {
            int col = tn + wc * 64 + n * 16 + (lane & 15);
            if (EPI == 0) {
                int which = col >> 10;
                int hh = (col >> 6) & 15;
                int d = col & 63;
                int b0 = row >> 11;
                int nn = row & 2047;             // nn % 4 == 0
                size_t bh = (size_t)(b0 * 16 + hh);
                if (which == 2) {
                    int i6 = nn & 63;
                    int pc = (nn & ~63) + ((i6 >> 2) & 3) * 16 + ((i6 >> 4) & 3) * 4;
                    ushort4 st;
                    st.x = f2b(acc[m][n][0]);
                    st.y = f2b(acc[m][n][1]);
                    st.z = f2b(acc[m][n][2]);
                    st.w = f2b(acc[m][n][3]);
                    *(ushort4*)(outV + bh * 131072 + (size_t)d * 2048 + pc) = st;
                } else if (which == 0) {
                    size_t off = (bh * 2048 + nn) * 64 + d;
#pragma unroll
                    for (int r = 0; r < 4; r++)
                        outQ[off + (size_t)r * 64] = f2b(acc[m][n][r] * 0.125f);
                } else {
                    size_t off = (bh * 2048 + nn) * 64 + d;
#pragma unroll
                    for (int r = 0; r < 4; r++)
                        outK[off + (size_t)r * 64] = f2b(acc[m][n][r]);
                }
            } else {
#pragma unroll
                for (int r = 0; r < 4; r++)
                    outF[(size_t)(row + r) * N + col] = acc[m][n][r];
            }
        }
    }
}

// ---------------- flash attention: softcap + causal + gate ----------------
// LDS-shared K/V; PAIRED 64-tiles: two tiles staged per barrier interval
// (64KB LDS) -> barrier count halved, prefetch distance doubled.
// Poly softcap (LOG2E folded); diagonal confined to the final pair;
// s_setprio(1) around MFMA clusters.
// 512 blocks = 32 bh x 16 pairs ({p,31-p}, balanced); 4 waves x 16 q-rows.

__global__ __launch_bounds__(256)
void attn_kernel(const unsigned short* __restrict__ Q,
                 const unsigned short* __restrict__ Kg,
                 const unsigned short* __restrict__ Vp,
                 const float* __restrict__ Gates,
                 unsigned short* __restrict__ Out) {
    __shared__ unsigned short lds[2][2][2][64][64];  // [dbuf][slot][K|V][row][col] = 64KB

    const int lane = threadIdx.x & 63;
    const int w = threadIdx.x >> 6;
    const int g = lane >> 4;
    const int ql = lane & 15;
    const int sw = ql & 7;
    const int srow = lane >> 3;
    const int sch = lane & 7;

    const int wgid = (blockIdx.x & 7) * 64 + (blockIdx.x >> 3);
    const int bh = wgid >> 4;
    const int pair = wgid & 15;
    const int b = bh >> 4;
    const int h = bh & 15;

    const size_t headBase = (size_t)bh * 2048 * 64;
    const size_t vBase = (size_t)bh * 131072;

    const int koff0 = ((g) ^ sw) * 8;
    const int koff1 = ((g + 4) ^ sw) * 8;
    const int voff0 = ((2 * g) ^ sw) * 8;
    const int voff1 = ((2 * g + 1) ^ sw) * 8;

    const int ch = sch ^ srow;
    const unsigned short* kSt0 = Kg + headBase + (size_t)(w * 16 + srow) * 64 + ch * 8;
    const unsigned short* kSt1 = kSt0 + 8 * 64;
    const unsigned short* vSt0 = Vp + vBase + (size_t)(w * 16 + srow) * 2048 + ch * 8;
    const unsigned short* vSt1 = vSt0 + 8 * 2048;

    auto STAGE = [&](int jn, int buf, int slot) {
        gload_lds16(kSt0 + (size_t)jn * 4096, (void*)&lds[buf][slot][0][w * 16][0]);
        gload_lds16(kSt1 + (size_t)jn * 4096, (void*)&lds[buf][slot][0][w * 16 + 8][0]);
        gload_lds16(vSt0 + jn * 64, (void*)&lds[buf][slot][1][w * 16][0]);
        gload_lds16(vSt1 + jn * 64, (void*)&lds[buf][slot][1][w * 16 + 8][0]);
    };

    const float LOG2E = 1.4426950408889634f;
    const float LC1 = -1.9235933878519511e-4f;   // LOG2E * -(1/3)/2500
    const float LC2 = 3.0777494205631219e-8f;    // LOG2E * (2/15)/2500^2

    for (int half = 0; half < 2; half++) {
        const int qt = half ? (31 - pair) : pair;
        const int qglob = qt * 64 + w * 16 + ql;
        const int T = qt + 1;
        const int nPairs = (T + 1) >> 1;

        const unsigned short* qp = Q + headBase + (size_t)qglob * 64 + g * 8;
        bf16x8 qa0 = *(const bf16x8*)qp;
        bf16x8 qa1 = *(const bf16x8*)(qp + 32);

        float lsum = 0.f;
        f32x4 o[4];
#pragma unroll
        for (int n = 0; n < 4; n++) o[n] = (f32x4){0.f, 0.f, 0.f, 0.f};

        auto COMPUTE = [&](int jt, int bb, int slot, bool diag) {
            const unsigned short* KL = &lds[bb][slot][0][0][0];
            const unsigned short* VL = &lds[bb][slot][1][0][0];

            f32x4 s4[4];
            __builtin_amdgcn_s_setprio(1);
#pragma unroll
            for (int n = 0; n < 4; n++) {
                const unsigned short* kr = KL + (16 * n + ql) * 64;
                bf16x8 k0 = *(const bf16x8*)(kr + koff0);
                bf16x8 k1 = *(const bf16x8*)(kr + koff1);
                f32x4 sv = (f32x4){0.f, 0.f, 0.f, 0.f};
                sv = __builtin_amdgcn_mfma_f32_16x16x32_bf16(k0, qa0, sv, 0, 0, 0);
                sv = __builtin_amdgcn_mfma_f32_16x16x32_bf16(k1, qa1, sv, 0, 0, 0);
                s4[n] = sv;
            }
            __builtin_amdgcn_s_setprio(0);

            float rs = 0.f;
#pragma unroll
            for (int n = 0; n < 4; n++) {
                int k0c = jt * 64 + n * 16 + 4 * g;
#pragma unroll
                for (int r = 0; r < 4; r++) {
                    float xx = s4[n][r];
                    float x2 = xx * xx;
                    float e2 = xx * __builtin_fmaf(x2, __builtin_fmaf(x2, LC2, LC1), LOG2E);
                    if (diag && (k0c + r > qglob)) e2 = -1e30f;
                    float p = __builtin_amdgcn_exp2f(e2);
                    s4[n][r] = p;
                    rs += p;
                }
            }
            lsum += rs;

            union PU { unsigned int u[4]; bf16x8 v; };
            PU p0, p1;
            p0.u[0] = cvtpk(s4[0][0], s4[0][1]);
            p0.u[1] = cvtpk(s4[0][2], s4[0][3]);
            p0.u[2] = cvtpk(s4[1][0], s4[1][1]);
            p0.u[3] = cvtpk(s4[1][2], s4[1][3]);
            p1.u[0] = cvtpk(s4[2][0], s4[2][1]);
            p1.u[1] = cvtpk(s4[2][2], s4[2][3]);
            p1.u[2] = cvtpk(s4[3][0], s4[3][1]);
            p1.u[3] = cvtpk(s4[3][2], s4[3][3]);

            __builtin_amdgcn_s_setprio(1);
#pragma unroll
            for (int n = 0; n < 4; n++) {
                const unsigned short* vr = VL + (16 * n + ql) * 64;
                bf16x8 vA = *(const bf16x8*)(vr + voff0);
                bf16x8 vB = *(const bf16x8*)(vr + voff1);
                o[n] = __builtin_amdgcn_mfma_f32_16x16x32_bf16(vA, p0.v, o[n], 0, 0, 0);
                o[n] = __builtin_amdgcn_mfma_f32_16x16x32_bf16(vB, p1.v, o[n], 0, 0, 0);
            }
            __builtin_amdgcn_s_setprio(0);
        };

        STAGE(0, 0, 0);
        if (1 <= qt) STAGE(1, 0, 1);
        __syncthreads();

        for (int p = 0; p < nPairs - 1; ++p) {
            const int bb = p & 1;
            const int j2 = 2 * (p + 1);
            STAGE(j2, bb ^ 1, 0);
            if (j2 + 1 <= qt) STAGE(j2 + 1, bb ^ 1, 1);
            COMPUTE(2 * p, bb, 0, false);
            COMPUTE(2 * p + 1, bb, 1, false);
            __syncthreads();
        }
        {
            const int p = nPairs - 1;
            const int bb = p & 1;
            COMPUTE(2 * p, bb, 0, 2 * p == qt);
            if (2 * p + 1 <= qt) COMPUTE(2 * p + 1, bb, 1, true);
            __syncthreads();
        }

        float l = lsum;
        l += __shfl_xor(l, 16);
        l += __shfl_xor(l, 32);
        float gate = Gates[(size_t)bh * 2048 + qglob];
        float inv = gate / l;
        unsigned short* orow = Out + ((size_t)(b * 2048) + qglob) * 1024 + h * 64;
#pragma unroll
        for (int n = 0; n < 4; n++) {
            ushort4 st;
            st.x = f2b(o[n][0] * inv);
            st.y = f2b(o[n][1] * inv);
            st.z = f2b(o[n][2] * inv);
            st.w = f2b(o[n][3] * inv);
            *(ushort4*)(orow + n * 16 + 4 * g) = st;
        }
    }
}

// ---------------- launch ----------------

extern "C" void kernel_launch(void* const* d_in, const int* in_sizes, int n_in,
                              void* d_out, int out_size, void* d_ws, size_t ws_size,
                              hipStream_t stream) {
    const float* x       = (const float*)d_in[0];   // [2][2048][1024]
    const float* w_qkv   = (const float*)d_in[1];   // [1024][3072]
    const float* w_gates = (const float*)d_in[2];   // [1024][16]
    const float* w_out   = (const float*)d_in[3];   // [1024][1024]
    float* out = (float*)d_out;                     // [2][2048][1024]

    char* ws = (char*)d_ws;
    unsigned short* x_bf  = (unsigned short*)(ws);                      // 8 MB
    unsigned short* wqkvT = (unsigned short*)(ws + ((size_t)8  << 20)); // 6 MB
    unsigned short* woutT = (unsigned short*)(ws + ((size_t)14 << 20)); // 2 MB
    unsigned short* qB    = (unsigned short*)(ws + ((size_t)16 << 20)); // 8 MB
    unsigned short* kB    = (unsigned short*)(ws + ((size_t)24 << 20)); // 8 MB
    unsigned short* vP    = (unsigned short*)(ws + ((size_t)32 << 20)); // 8 MB (permuted V)
    float*          gates = (float*)(ws + ((size_t)40 << 20));          // 256 KB
    unsigned short* attnO = (unsigned short*)(ws + ((size_t)41 << 20)); // 8 MB

    prepass_kernel<<<dim3(8192), dim3(256), 0, stream>>>(
        x, w_gates, w_qkv, w_out, x_bf, gates, wqkvT, woutT);

    gemm_bt_kernel<0, 2><<<dim3(3072 / 128, 4096 / 128), dim3(256), 0, stream>>>(
        x_bf, wqkvT, 4096, 3072, 1024, qB, kB, vP, (float*)nullptr);

    attn_kernel<<<dim3(512), dim3(256), 0, stream>>>(qB, kB, vP, gates, attnO);

    gemm_bt_kernel<1, 1><<<dim3(1024 / 64, 4096 / 128), dim3(256), 0, stream>>>(
        attnO, woutT, 4096, 1024, 1024, nullptr, nullptr, nullptr, out);
}

// Round 19
// 109.006 us; speedup vs baseline: 2.3939x; 1.1659x over previous
//
#include <hip/hip_runtime.h>
#include <hip/hip_bf16.h>

typedef __bf16 bf16x8 __attribute__((ext_vector_type(8)));
typedef float f32x4 __attribute__((ext_vector_type(4)));

__device__ __forceinline__ unsigned short f2b(float f) {
    union { float f; unsigned int u; } v; v.f = f;
    unsigned int r = (v.u + 0x7FFFu + ((v.u >> 16) & 1u)) >> 16;
    return (unsigned short)r;
}

__device__ __forceinline__ unsigned int cvtpk(float lo, float hi) {
    unsigned int r;
    asm("v_cvt_pk_bf16_f32 %0, %1, %2" : "=v"(r) : "v"(lo), "v"(hi));
    return r;
}

__device__ __forceinline__ void gload_lds16(const void* g, void* l) {
    __builtin_amdgcn_global_load_lds((__attribute__((address_space(1))) void*)g,
                                     (__attribute__((address_space(3))) void*)l,
                                     16, 0, 0);
}

// ---- prepass: pure-streaming convert + transposes (no GEMV) ----
// blocks 0..2047:     x -> bf16 (grid-stride float4 pairs)
// blocks 2048..6143:  weight transposes (w_qkv, w_out)
// blocks 6144..6147:  w_gates -> wgT[16][1024] bf16

__global__ __launch_bounds__(256)
void prepass_kernel(const float* __restrict__ x, const float* __restrict__ wg,
                    const float* __restrict__ wq, const float* __restrict__ wo,
                    unsigned short* __restrict__ xb,
                    unsigned short* __restrict__ outq, unsigned short* __restrict__ outo,
                    unsigned short* __restrict__ wgT) {
    __shared__ float tt[32][33];
    const int t = threadIdx.x;
    if (blockIdx.x < 2048) {
        size_t idx = ((size_t)blockIdx.x * 256 + t) * 8;
        float4 f0 = *(const float4*)(x + idx);
        float4 f1 = *(const float4*)(x + idx + 4);
        ushort4 u0, u1;
        u0.x = f2b(f0.x); u0.y = f2b(f0.y); u0.z = f2b(f0.z); u0.w = f2b(f0.w);
        u1.x = f2b(f1.x); u1.y = f2b(f1.y); u1.z = f2b(f1.z); u1.w = f2b(f1.w);
        *(ushort4*)(xb + idx) = u0;
        *(ushort4*)(xb + idx + 4) = u1;
    } else if (blockIdx.x < 6144) {
        const int bx = blockIdx.x - 2048;    // 0..4095
        const int colTile = bx & 127;
        const int r0 = (bx >> 7) * 32;       // R = 1024
        const float* in;
        unsigned short* out;
        int C, c0;
        if (colTile < 96) { in = wq; out = outq; C = 3072; c0 = colTile * 32; }
        else              { in = wo; out = outo; C = 1024; c0 = (colTile - 96) * 32; }
        const int tx = t & 31, ty = t >> 5;
#pragma unroll
        for (int i = 0; i < 4; i++)
            tt[ty + i * 8][tx] = in[(size_t)(r0 + ty + i * 8) * C + c0 + tx];
        __syncthreads();
#pragma unroll
        for (int i = 0; i < 4; i++)
            out[(size_t)(c0 + ty + i * 8) * 1024 + r0 + tx] = f2b(tt[tx][ty + i * 8]);
    } else {
        const int local = blockIdx.x - 6144;        // 0..3
        const int base = local * 4096 + t * 16;     // element index into wg (f*16+h)
        const int f = base >> 4;
#pragma unroll
        for (int j = 0; j < 16; j++)
            wgT[j * 1024 + f] = f2b(wg[base + j]);  // h = j
    }
}

// ---- gates via MFMA: gates[b*16+h][n] = sigmoid((x @ wg)[n,h]) ----
// 256 blocks (16 rows each) x 4 waves (K split 4x256), LDS combine.

__global__ __launch_bounds__(256)
void gates_mfma_kernel(const unsigned short* __restrict__ xb,
                       const unsigned short* __restrict__ wgT,
                       float* __restrict__ gates) {
    __shared__ float comb[4][16][16];
    const int lane = threadIdx.x & 63;
    const int w = threadIdx.x >> 6;
    const int ql = lane & 15;
    const int g = lane >> 4;
    const int n0 = blockIdx.x * 16;

    f32x4 acc = (f32x4){0.f, 0.f, 0.f, 0.f};
    const int kb = w * 256;
#pragma unroll
    for (int kk = 0; kk < 256; kk += 32) {
        bf16x8 a = *(const bf16x8*)(wgT + ql * 1024 + kb + kk + g * 8);
        bf16x8 bfr = *(const bf16x8*)(xb + (size_t)(n0 + ql) * 1024 + kb + kk + g * 8);
        acc = __builtin_amdgcn_mfma_f32_16x16x32_bf16(a, bfr, acc, 0, 0, 0);
    }
#pragma unroll
    for (int r = 0; r < 4; r++) comb[w][g * 4 + r][ql] = acc[r];
    __syncthreads();
    if (w == 0) {
        const float LOG2E = 1.4426950408889634f;
        int row = n0 + ql;
        int b = row >> 11, n = row & 2047;
#pragma unroll
        for (int r = 0; r < 4; r++) {
            int h = g * 4 + r;
            float tot = comb[0][h][ql] + comb[1][h][ql] + comb[2][h][ql] + comb[3][h][ql];
            float sg = __builtin_amdgcn_rcpf(1.f + __builtin_amdgcn_exp2f(-tot * LOG2E));
            gates[((size_t)(b * 16 + h)) * 2048 + n] = sg;
        }
    }
}

// ---------------- GEMM: C = A[M][K] * Bt[N][K]^T, bf16 in, fp32 acc ----------------
// BK=32, double-buffered staging (one barrier/iter). WN=2: 128x128; WN=1: 128x64.
// EPI 0: Q (x0.125), K as [b][h][n][d]; V directly in Vp[bh][d][permC(nn)].
// EPI 1: fp32 out [M][N].

template <int EPI, int WN>
__global__ __launch_bounds__(256)
void gemm_bt_kernel(const unsigned short* __restrict__ A,
                    const unsigned short* __restrict__ Bt,
                    int M, int N, int K,
                    unsigned short* __restrict__ outQ,
                    unsigned short* __restrict__ outK,
                    unsigned short* __restrict__ outV,
                    float* __restrict__ outF) {
    constexpr int WM = 4 / WN;
    constexpr int MF = 8 / WM;
    constexpr int BN = 64 * WN;
    __shared__ unsigned short As[2][128 * 32];
    __shared__ unsigned short Bs[2][BN * 32];
    const int lane = threadIdx.x & 63;
    const int w = threadIdx.x >> 6;
    const int wr = w / WN, wc = w % WN;
    const int tm = blockIdx.y * 128;
    const int tn = blockIdx.x * BN;

    f32x4 acc[MF][4];
#pragma unroll
    for (int m = 0; m < MF; m++)
#pragma unroll
        for (int n = 0; n < 4; n++) acc[m][n] = (f32x4){0.f, 0.f, 0.f, 0.f};

    const int sRow = lane >> 2;
    const int sCol = (lane & 3) * 8;
    const int fragA = (wr * (16 * MF) + (lane & 15)) * 32 + (lane >> 4) * 8;
    const int fragB = (wc * 64 + (lane & 15)) * 32 + (lane >> 4) * 8;

    auto STAGE = [&](int k0, int buf) {
#pragma unroll
        for (int i = 0; i < 2; i++) {
            int chunk = w * 2 + i;
            int r = chunk * 16 + sRow;
            gload_lds16(A + (size_t)(tm + r) * K + k0 + sCol, (void*)(As[buf] + chunk * 512));
            if (WN == 2)
                gload_lds16(Bt + (size_t)(tn + r) * K + k0 + sCol, (void*)(Bs[buf] + chunk * 512));
        }
        if (WN == 1) {
            int r = w * 16 + sRow;
            gload_lds16(Bt + (size_t)(tn + r) * K + k0 + sCol, (void*)(Bs[buf] + w * 512));
        }
    };

    STAGE(0, 0);
    __syncthreads();
    int cur = 0;
    for (int k0 = 0; k0 < K; k0 += 32) {
        if (k0 + 32 < K) STAGE(k0 + 32, cur ^ 1);
        bf16x8 af[MF], bg[4];
#pragma unroll
        for (int m = 0; m < MF; m++) af[m] = *(const bf16x8*)(As[cur] + fragA + m * 16 * 32);
#pragma unroll
        for (int n = 0; n < 4; n++) bg[n] = *(const bf16x8*)(Bs[cur] + fragB + n * 16 * 32);
#pragma unroll
        for (int m = 0; m < MF; m++)
#pragma unroll
            for (int n = 0; n < 4; n++)
                acc[m][n] = __builtin_amdgcn_mfma_f32_16x16x32_bf16(af[m], bg[n], acc[m][n], 0, 0, 0);
        __syncthreads();
        cur ^= 1;
    }

#pragma unroll
    for (int m = 0; m < MF; m++) {
        int row = tm + wr * (16 * MF) + m * 16 + (lane >> 4) * 4;
#pragma unroll
        for (int n = 0; n < 4; n++) {
            int col = tn + wc * 64 + n * 16 + (lane & 15);
            if (EPI == 0) {
                int which = col >> 10;
                int hh = (col >> 6) & 15;
                int d = col & 63;
                int b0 = row >> 11;
                int nn = row & 2047;             // nn % 4 == 0
                size_t bh = (size_t)(b0 * 16 + hh);
                if (which == 2) {
                    int i6 = nn & 63;
                    int pc = (nn & ~63) + ((i6 >> 2) & 3) * 16 + ((i6 >> 4) & 3) * 4;
                    ushort4 st;
                    st.x = f2b(acc[m][n][0]);
                    st.y = f2b(acc[m][n][1]);
                    st.z = f2b(acc[m][n][2]);
                    st.w = f2b(acc[m][n][3]);
                    *(ushort4*)(outV + bh * 131072 + (size_t)d * 2048 + pc) = st;
                } else if (which == 0) {
                    size_t off = (bh * 2048 + nn) * 64 + d;
#pragma unroll
                    for (int r = 0; r < 4; r++)
                        outQ[off + (size_t)r * 64] = f2b(acc[m][n][r] * 0.125f);
                } else {
                    size_t off = (bh * 2048 + nn) * 64 + d;
#pragma unroll
                    for (int r = 0; r < 4; r++)
                        outK[off + (size_t)r * 64] = f2b(acc[m][n][r]);
                }
            } else {
#pragma unroll
                for (int r = 0; r < 4; r++)
                    outF[(size_t)(row + r) * N + col] = acc[m][n][r];
            }
        }
    }
}

// ---------------- flash attention: softcap + causal + gate ----------------
// LDS-shared K/V; paired 64-tiles (64KB LDS), double-buffered, XOR-swizzled
// ds_read_b128; poly softcap (LOG2E folded); diagonal confined to final pair;
// s_setprio around MFMA clusters. 512 blocks = 32 bh x 16 pairs; 4 waves.

__global__ __launch_bounds__(256)
void attn_kernel(const unsigned short* __restrict__ Q,
                 const unsigned short* __restrict__ Kg,
                 const unsigned short* __restrict__ Vp,
                 const float* __restrict__ Gates,
                 unsigned short* __restrict__ Out) {
    __shared__ unsigned short lds[2][2][2][64][64];  // [dbuf][slot][K|V][row][col] = 64KB

    const int lane = threadIdx.x & 63;
    const int w = threadIdx.x >> 6;
    const int g = lane >> 4;
    const int ql = lane & 15;
    const int sw = ql & 7;
    const int srow = lane >> 3;
    const int sch = lane & 7;

    const int wgid = (blockIdx.x & 7) * 64 + (blockIdx.x >> 3);
    const int bh = wgid >> 4;
    const int pair = wgid & 15;
    const int b = bh >> 4;
    const int h = bh & 15;

    const size_t headBase = (size_t)bh * 2048 * 64;
    const size_t vBase = (size_t)bh * 131072;

    const int koff0 = ((g) ^ sw) * 8;
    const int koff1 = ((g + 4) ^ sw) * 8;
    const int voff0 = ((2 * g) ^ sw) * 8;
    const int voff1 = ((2 * g + 1) ^ sw) * 8;

    const int ch = sch ^ srow;
    const unsigned short* kSt0 = Kg + headBase + (size_t)(w * 16 + srow) * 64 + ch * 8;
    const unsigned short* kSt1 = kSt0 + 8 * 64;
    const unsigned short* vSt0 = Vp + vBase + (size_t)(w * 16 + srow) * 2048 + ch * 8;
    const unsigned short* vSt1 = vSt0 + 8 * 2048;

    auto STAGE = [&](int jn, int buf, int slot) {
        gload_lds16(kSt0 + (size_t)jn * 4096, (void*)&lds[buf][slot][0][w * 16][0]);
        gload_lds16(kSt1 + (size_t)jn * 4096, (void*)&lds[buf][slot][0][w * 16 + 8][0]);
        gload_lds16(vSt0 + jn * 64, (void*)&lds[buf][slot][1][w * 16][0]);
        gload_lds16(vSt1 + jn * 64, (void*)&lds[buf][slot][1][w * 16 + 8][0]);
    };

    const float LOG2E = 1.4426950408889634f;
    const float LC1 = -1.9235933878519511e-4f;
    const float LC2 = 3.0777494205631219e-8f;

    for (int half = 0; half < 2; half++) {
        const int qt = half ? (31 - pair) : pair;
        const int qglob = qt * 64 + w * 16 + ql;
        const int T = qt + 1;
        const int nPairs = (T + 1) >> 1;

        const unsigned short* qp = Q + headBase + (size_t)qglob * 64 + g * 8;
        bf16x8 qa0 = *(const bf16x8*)qp;
        bf16x8 qa1 = *(const bf16x8*)(qp + 32);

        float lsum = 0.f;
        f32x4 o[4];
#pragma unroll
        for (int n = 0; n < 4; n++) o[n] = (f32x4){0.f, 0.f, 0.f, 0.f};

        auto COMPUTE = [&](int jt, int bb, int slot, bool diag) {
            const unsigned short* KL = &lds[bb][slot][0][0][0];
            const unsigned short* VL = &lds[bb][slot][1][0][0];

            f32x4 s4[4];
            __builtin_amdgcn_s_setprio(1);
#pragma unroll
            for (int n = 0; n < 4; n++) {
                const unsigned short* kr = KL + (16 * n + ql) * 64;
                bf16x8 k0 = *(const bf16x8*)(kr + koff0);
                bf16x8 k1 = *(const bf16x8*)(kr + koff1);
                f32x4 sv = (f32x4){0.f, 0.f, 0.f, 0.f};
                sv = __builtin_amdgcn_mfma_f32_16x16x32_bf16(k0, qa0, sv, 0, 0, 0);
                sv = __builtin_amdgcn_mfma_f32_16x16x32_bf16(k1, qa1, sv, 0, 0, 0);
                s4[n] = sv;
            }
            __builtin_amdgcn_s_setprio(0);

            float rs = 0.f;
#pragma unroll
            for (int n = 0; n < 4; n++) {
                int k0c = jt * 64 + n * 16 + 4 * g;
#pragma unroll
                for (int r = 0; r < 4; r++) {
                    float xx = s4[n][r];
                    float x2 = xx * xx;
                    float e2 = xx * __builtin_fmaf(x2, __builtin_fmaf(x2, LC2, LC1), LOG2E);
                    if (diag && (k0c + r > qglob)) e2 = -1e30f;
                    float p = __builtin_amdgcn_exp2f(e2);
                    s4[n][r] = p;
                    rs += p;
                }
            }
            lsum += rs;

            union PU { unsigned int u[4]; bf16x8 v; };
            PU p0, p1;
            p0.u[0] = cvtpk(s4[0][0], s4[0][1]);
            p0.u[1] = cvtpk(s4[0][2], s4[0][3]);
            p0.u[2] = cvtpk(s4[1][0], s4[1][1]);
            p0.u[3] = cvtpk(s4[1][2], s4[1][3]);
            p1.u[0] = cvtpk(s4[2][0], s4[2][1]);
            p1.u[1] = cvtpk(s4[2][2], s4[2][3]);
            p1.u[2] = cvtpk(s4[3][0], s4[3][1]);
            p1.u[3] = cvtpk(s4[3][2], s4[3][3]);

            __builtin_amdgcn_s_setprio(1);
#pragma unroll
            for (int n = 0; n < 4; n++) {
                const unsigned short* vr = VL + (16 * n + ql) * 64;
                bf16x8 vA = *(const bf16x8*)(vr + voff0);
                bf16x8 vB = *(const bf16x8*)(vr + voff1);
                o[n] = __builtin_amdgcn_mfma_f32_16x16x32_bf16(vA, p0.v, o[n], 0, 0, 0);
                o[n] = __builtin_amdgcn_mfma_f32_16x16x32_bf16(vB, p1.v, o[n], 0, 0, 0);
            }
            __builtin_amdgcn_s_setprio(0);
        };

        STAGE(0, 0, 0);
        if (1 <= qt) STAGE(1, 0, 1);
        __syncthreads();

        for (int p = 0; p < nPairs - 1; ++p) {
            const int bb = p & 1;
            const int j2 = 2 * (p + 1);
            STAGE(j2, bb ^ 1, 0);
            if (j2 + 1 <= qt) STAGE(j2 + 1, bb ^ 1, 1);
            COMPUTE(2 * p, bb, 0, false);
            COMPUTE(2 * p + 1, bb, 1, false);
            __syncthreads();
        }
        {
            const int p = nPairs - 1;
            const int bb = p & 1;
            COMPUTE(2 * p, bb, 0, 2 * p == qt);
            if (2 * p + 1 <= qt) COMPUTE(2 * p + 1, bb, 1, true);
            __syncthreads();
        }

        float l = lsum;
        l += __shfl_xor(l, 16);
        l += __shfl_xor(l, 32);
        float gate = Gates[(size_t)bh * 2048 + qglob];
        float inv = gate / l;
        unsigned short* orow = Out + ((size_t)(b * 2048) + qglob) * 1024 + h * 64;
#pragma unroll
        for (int n = 0; n < 4; n++) {
            ushort4 st;
            st.x = f2b(o[n][0] * inv);
            st.y = f2b(o[n][1] * inv);
            st.z = f2b(o[n][2] * inv);
            st.w = f2b(o[n][3] * inv);
            *(ushort4*)(orow + n * 16 + 4 * g) = st;
        }
    }
}

// ---------------- launch ----------------

extern "C" void kernel_launch(void* const* d_in, const int* in_sizes, int n_in,
                              void* d_out, int out_size, void* d_ws, size_t ws_size,
                              hipStream_t stream) {
    const float* x       = (const float*)d_in[0];   // [2][2048][1024]
    const float* w_qkv   = (const float*)d_in[1];   // [1024][3072]
    const float* w_gates = (const float*)d_in[2];   // [1024][16]
    const float* w_out   = (const float*)d_in[3];   // [1024][1024]
    float* out = (float*)d_out;                     // [2][2048][1024]

    char* ws = (char*)d_ws;
    unsigned short* x_bf  = (unsigned short*)(ws);                      // 8 MB
    unsigned short* wqkvT = (unsigned short*)(ws + ((size_t)8  << 20)); // 6 MB
    unsigned short* woutT = (unsigned short*)(ws + ((size_t)14 << 20)); // 2 MB
    unsigned short* qB    = (unsigned short*)(ws + ((size_t)16 << 20)); // 8 MB
    unsigned short* kB    = (unsigned short*)(ws + ((size_t)24 << 20)); // 8 MB
    unsigned short* vP    = (unsigned short*)(ws + ((size_t)32 << 20)); // 8 MB (permuted V)
    float*          gates = (float*)(ws + ((size_t)40 << 20));          // 256 KB
    unsigned short* wgT   = (unsigned short*)(ws + ((size_t)40 << 20) + (512 << 10)); // 32 KB
    unsigned short* attnO = (unsigned short*)(ws + ((size_t)41 << 20)); // 8 MB

    prepass_kernel<<<dim3(6148), dim3(256), 0, stream>>>(
        x, w_gates, w_qkv, w_out, x_bf, wqkvT, woutT, wgT);

    gates_mfma_kernel<<<dim3(256), dim3(256), 0, stream>>>(x_bf, wgT, gates);

    gemm_bt_kernel<0, 2><<<dim3(3072 / 128, 4096 / 128), dim3(256), 0, stream>>>(
        x_bf, wqkvT, 4096, 3072, 1024, qB, kB, vP, (float*)nullptr);

    attn_kernel<<<dim3(512), dim3(256), 0, stream>>>(qB, kB, vP, gates, attnO);

    gemm_bt_kernel<1, 1><<<dim3(1024 / 64, 4096 / 128), dim3(256), 0, stream>>>(
        attnO, woutT, 4096, 1024, 1024, nullptr, nullptr, nullptr, out);
}